// Round 1
// baseline (6989.375 us; speedup 1.0000x reference)
//
#include <hip/hip_runtime.h>
#include <hip/hip_bf16.h>

// Model: 1-layer transformer encoder vmapped over Ps experts (shared weights),
// then gated combine over Ps + linear head, output transposed to (B,PRED,C).
#define NT   49152   // Ps*B*C*L tokens
#define D_   512
#define DF_  2048
#define PS   6
#define BB   16
#define CC   8
#define LL   64
#define HH   8
#define DHD  64
#define PREDN 96

// ---------------------------------------------------------------------------
// Generic f32 GEMM: C[M,N] = A[M,K] @ W[K,N] + bias[N]  (optional ReLU)
// BM=BN=64, BK=16, 256 threads, 4x4 micro-tile, float4 LDS reads (pad to 68).
// M must be a multiple of 64 (true for all call sites); N,K multiples of 16.
// ---------------------------------------------------------------------------
template <bool RELU>
__global__ __launch_bounds__(256) void gemm_bias(
    const float* __restrict__ A, const float* __restrict__ W,
    const float* __restrict__ bias, float* __restrict__ Cout,
    int M, int N, int K) {
  __shared__ float As[16][68];   // As[k][m]
  __shared__ float Bs[16][68];   // Bs[k][n]
  const int bm = blockIdx.x * 64;
  const int bn = blockIdx.y * 64;
  const int tid = threadIdx.x;
  const int tr = (tid >> 4) * 4;
  const int tc = (tid & 15) * 4;
  float acc[4][4] = {};
  for (int k0 = 0; k0 < K; k0 += 16) {
#pragma unroll
    for (int j = 0; j < 4; ++j) {
      int e = tid + j * 256;
      int m = e >> 4, kk = e & 15;
      As[kk][m] = A[(size_t)(bm + m) * K + (k0 + kk)];
      int kk2 = e >> 6, n = e & 63;
      Bs[kk2][n] = (bn + n < N) ? W[(size_t)(k0 + kk2) * N + (bn + n)] : 0.f;
    }
    __syncthreads();
#pragma unroll
    for (int kk = 0; kk < 16; ++kk) {
      float4 a4 = *(const float4*)&As[kk][tr];
      float4 b4 = *(const float4*)&Bs[kk][tc];
      float av[4] = {a4.x, a4.y, a4.z, a4.w};
      float bv[4] = {b4.x, b4.y, b4.z, b4.w};
#pragma unroll
      for (int i = 0; i < 4; ++i)
#pragma unroll
        for (int j = 0; j < 4; ++j) acc[i][j] += av[i] * bv[j];
    }
    __syncthreads();
  }
#pragma unroll
  for (int i = 0; i < 4; ++i) {
    int m = bm + tr + i;
#pragma unroll
    for (int j = 0; j < 4; ++j) {
      int n = bn + tc + j;
      if (n < N) {
        float v = acc[i][j] + bias[n];
        if (RELU) v = fmaxf(v, 0.f);
        Cout[(size_t)m * N + n] = v;
      }
    }
  }
}

// ---------------------------------------------------------------------------
// Attention over sequence axis (S=L=64, dh=64). One block per (group, head).
// group g = (p*B+b)*C+c covers token rows g*64..g*64+63.
// O may alias Q (reads staged through LDS; blocks touch disjoint regions).
// ---------------------------------------------------------------------------
__global__ __launch_bounds__(256) void attn_seq(
    const float* __restrict__ Q, const float* __restrict__ K,
    const float* __restrict__ V, float* __restrict__ O) {
  __shared__ float qs[64][65];   // Q tile, later reused as P (scores)
  __shared__ float ks[64][65];
  __shared__ float vs[64][64];
  const int h = blockIdx.x & 7;
  const int g = blockIdx.x >> 3;
  const size_t base = (size_t)g * 64 * D_ + h * DHD;
  const int tid = threadIdx.x;
#pragma unroll
  for (int j = 0; j < 16; ++j) {
    int e = tid + j * 256;
    int l = e >> 6, d = e & 63;
    size_t idx = base + (size_t)l * D_ + d;
    qs[l][d] = Q[idx];
    ks[l][d] = K[idx];
    vs[l][d] = V[idx];
  }
  __syncthreads();
  float sc[16];
#pragma unroll
  for (int j = 0; j < 16; ++j) {
    int e = tid + j * 256;
    int i = e >> 6, t = e & 63;
    float s = 0.f;
#pragma unroll
    for (int d = 0; d < 64; ++d) s += qs[i][d] * ks[t][d];
    sc[j] = s * 0.125f;  // 1/sqrt(dh=64)
  }
  __syncthreads();
#pragma unroll
  for (int j = 0; j < 16; ++j) {
    int e = tid + j * 256;
    qs[e >> 6][e & 63] = sc[j];   // qs now holds S
  }
  __syncthreads();
  if (tid < 64) {  // row-wise softmax (64 rows)
    float mx = -1e30f;
#pragma unroll
    for (int t = 0; t < 64; ++t) mx = fmaxf(mx, qs[tid][t]);
    float sum = 0.f;
#pragma unroll
    for (int t = 0; t < 64; ++t) { float e = __expf(qs[tid][t] - mx); qs[tid][t] = e; sum += e; }
    float inv = 1.f / sum;
#pragma unroll
    for (int t = 0; t < 64; ++t) qs[tid][t] *= inv;
  }
  __syncthreads();
#pragma unroll
  for (int j = 0; j < 16; ++j) {
    int e = tid + j * 256;
    int i = e >> 6, d = e & 63;
    float s = 0.f;
#pragma unroll
    for (int t = 0; t < 64; ++t) s += qs[i][t] * vs[t][d];
    O[base + (size_t)i * D_ + d] = s;
  }
}

// ---------------------------------------------------------------------------
// Attention over context axis (S=C=8, dh=64), i.e. the swapaxes(1,2) MHA.
// One 64-thread block per (pb, l, h); c-axis rows are stride-64 token rows.
// ---------------------------------------------------------------------------
__global__ __launch_bounds__(64) void attn_ctx(
    const float* __restrict__ Q, const float* __restrict__ K,
    const float* __restrict__ V, float* __restrict__ O) {
  __shared__ float qs[8][65], ks[8][65], vs[8][65], ps[8][9];
  const int h = blockIdx.x & 7;
  const int l = (blockIdx.x >> 3) & 63;
  const int pb = blockIdx.x >> 9;          // 0..95 = p*B+b
  const size_t row0 = (size_t)pb * 512 + l;  // token row for c=0
  const int tid = threadIdx.x;  // 64
#pragma unroll
  for (int c = 0; c < 8; ++c) {
    size_t idx = (row0 + (size_t)c * 64) * D_ + h * DHD + tid;
    qs[c][tid] = Q[idx];
    ks[c][tid] = K[idx];
    vs[c][tid] = V[idx];
  }
  __syncthreads();
  {
    int i = tid >> 3, t = tid & 7;
    float s = 0.f;
#pragma unroll
    for (int d = 0; d < 64; ++d) s += qs[i][d] * ks[t][d];
    ps[i][t] = s * 0.125f;
  }
  __syncthreads();
  if (tid < 8) {
    float mx = -1e30f;
#pragma unroll
    for (int t = 0; t < 8; ++t) mx = fmaxf(mx, ps[tid][t]);
    float sum = 0.f;
#pragma unroll
    for (int t = 0; t < 8; ++t) { float e = __expf(ps[tid][t] - mx); ps[tid][t] = e; sum += e; }
    float inv = 1.f / sum;
#pragma unroll
    for (int t = 0; t < 8; ++t) ps[tid][t] *= inv;
  }
  __syncthreads();
#pragma unroll
  for (int c = 0; c < 8; ++c) {
    float s = 0.f;
#pragma unroll
    for (int t = 0; t < 8; ++t) s += ps[c][t] * vs[t][tid];
    O[(row0 + (size_t)c * 64) * D_ + h * DHD + tid] = s;
  }
}

// ---------------------------------------------------------------------------
// Xout = LayerNorm(Xin + T) * g + b   (row length 512, one 256-thread block/row)
// Xin may alias Xout (each thread reads its own elements before writing).
// ---------------------------------------------------------------------------
__global__ __launch_bounds__(256) void add_ln(
    const float* __restrict__ Xin, const float* __restrict__ T,
    float* __restrict__ Xout,
    const float* __restrict__ g, const float* __restrict__ b) {
  const size_t off = (size_t)blockIdx.x * D_;
  const int tid = threadIdx.x;
  float x0 = Xin[off + tid] + T[off + tid];
  float x1 = Xin[off + tid + 256] + T[off + tid + 256];
  float s = x0 + x1, q = x0 * x0 + x1 * x1;
#pragma unroll
  for (int o = 32; o > 0; o >>= 1) { s += __shfl_down(s, o); q += __shfl_down(q, o); }
  __shared__ float ssum[4], sqsum[4];
  if ((tid & 63) == 0) { ssum[tid >> 6] = s; sqsum[tid >> 6] = q; }
  __syncthreads();
  float S = ssum[0] + ssum[1] + ssum[2] + ssum[3];
  float Qs = sqsum[0] + sqsum[1] + sqsum[2] + sqsum[3];
  float m = S * (1.f / D_);
  float var = Qs * (1.f / D_) - m * m;
  float inv = rsqrtf(var + 1e-5f);
  Xout[off + tid] = (x0 - m) * inv * g[tid] + b[tid];
  Xout[off + tid + 256] = (x1 - m) * inv * g[tid + 256] + b[tid + 256];
}

// ---------------------------------------------------------------------------
// combined[b,c,:] = sum_p gates[b,p] * X[(p*B+b)*C*L + c*L + (L-1), :]
// ---------------------------------------------------------------------------
__global__ __launch_bounds__(512) void combine_last(
    const float* __restrict__ X, const float* __restrict__ gates,
    float* __restrict__ comb) {
  const int b = blockIdx.x >> 3, c = blockIdx.x & 7;
  const int d = threadIdx.x;
  float s = 0.f;
#pragma unroll
  for (int p = 0; p < PS; ++p) {
    size_t row = ((size_t)(p * BB + b) * CC + c) * LL + (LL - 1);
    s += gates[b * PS + p] * X[row * D_ + d];
  }
  comb[(size_t)blockIdx.x * D_ + d] = s;
}

// out[b, n, c] = comb[b,c,:] @ hW[:,n] + hb[n]
__global__ __launch_bounds__(128) void head_kernel(
    const float* __restrict__ comb, const float* __restrict__ hW,
    const float* __restrict__ hb, float* __restrict__ out) {
  __shared__ float xr[D_];
  const int bc = blockIdx.x;  // b*8+c
  for (int i = threadIdx.x; i < D_; i += 128) xr[i] = comb[(size_t)bc * D_ + i];
  __syncthreads();
  const int n = threadIdx.x;
  if (n < PREDN) {
    float s = hb[n];
    for (int d = 0; d < D_; ++d) s += xr[d] * hW[d * PREDN + n];
    const int b = bc >> 3, c = bc & 7;
    out[((size_t)b * PREDN + n) * CC + c] = s;
  }
}

// ---------------------------------------------------------------------------
extern "C" void kernel_launch(void* const* d_in, const int* in_sizes, int n_in,
                              void* d_out, int out_size, void* d_ws, size_t ws_size,
                              hipStream_t stream) {
  const float* ex    = (const float*)d_in[0];
  const float* gates = (const float*)d_in[1];
  const float* cWq = (const float*)d_in[2];  const float* cbq = (const float*)d_in[3];
  const float* cWk = (const float*)d_in[4];  const float* cbk = (const float*)d_in[5];
  const float* cWv = (const float*)d_in[6];  const float* cbv = (const float*)d_in[7];
  const float* cWo = (const float*)d_in[8];  const float* cbo = (const float*)d_in[9];
  const float* iWq = (const float*)d_in[10]; const float* ibq = (const float*)d_in[11];
  const float* iWk = (const float*)d_in[12]; const float* ibk = (const float*)d_in[13];
  const float* iWv = (const float*)d_in[14]; const float* ibv = (const float*)d_in[15];
  const float* iWo = (const float*)d_in[16]; const float* ibo = (const float*)d_in[17];
  const float* mW1 = (const float*)d_in[18]; const float* mb1 = (const float*)d_in[19];
  const float* mW2 = (const float*)d_in[20]; const float* mb2 = (const float*)d_in[21];
  const float* g1  = (const float*)d_in[22]; const float* b1  = (const float*)d_in[23];
  const float* g3  = (const float*)d_in[24]; const float* b3  = (const float*)d_in[25];
  const float* g4  = (const float*)d_in[26]; const float* b4  = (const float*)d_in[27];
  const float* hW  = (const float*)d_in[28]; const float* hb  = (const float*)d_in[29];
  float* out = (float*)d_out;

  // Workspace: X | Q | K | V  (each NT*D f32 = 100.7 MB; total ~403 MB)
  float* X  = (float*)d_ws;
  float* Qb = X + (size_t)NT * D_;
  float* Kb = Qb + (size_t)NT * D_;
  float* Vb = Kb + (size_t)NT * D_;

  dim3 blk(256);
  dim3 g512(NT / 64, D_ / 64);

  // ---- cross attention (over L) ----
  gemm_bias<false><<<g512, blk, 0, stream>>>(ex, cWq, cbq, Qb, NT, D_, D_);
  gemm_bias<false><<<g512, blk, 0, stream>>>(ex, cWk, cbk, Kb, NT, D_, D_);
  gemm_bias<false><<<g512, blk, 0, stream>>>(ex, cWv, cbv, Vb, NT, D_, D_);
  attn_seq<<<dim3(768 * 8), blk, 0, stream>>>(Qb, Kb, Vb, Qb);
  gemm_bias<false><<<g512, blk, 0, stream>>>(Qb, cWo, cbo, Kb, NT, D_, D_);
  add_ln<<<dim3(NT), blk, 0, stream>>>(ex, Kb, X, g1, b1);

  // ---- inner attention (over C, the swapaxes path) ----
  gemm_bias<false><<<g512, blk, 0, stream>>>(X, iWq, ibq, Qb, NT, D_, D_);
  gemm_bias<false><<<g512, blk, 0, stream>>>(X, iWk, ibk, Kb, NT, D_, D_);
  gemm_bias<false><<<g512, blk, 0, stream>>>(X, iWv, ibv, Vb, NT, D_, D_);
  attn_ctx<<<dim3(NT), dim3(64), 0, stream>>>(Qb, Kb, Vb, Qb);
  gemm_bias<false><<<g512, blk, 0, stream>>>(Qb, iWo, ibo, Kb, NT, D_, D_);
  add_ln<<<dim3(NT), blk, 0, stream>>>(X, Kb, X, g3, b3);

  // ---- MLP in two token-halves: hidden (201 MB) reuses contiguous Q..K ----
  const int MH = NT / 2;
  for (int half = 0; half < 2; ++half) {
    const float* Xh = X + (size_t)half * MH * D_;
    float* Hh = Qb;
    float* Th = Vb + (size_t)half * MH * D_;
    gemm_bias<true><<<dim3(MH / 64, DF_ / 64), blk, 0, stream>>>(Xh, mW1, mb1, Hh, MH, DF_, D_);
    gemm_bias<false><<<dim3(MH / 64, D_ / 64), blk, 0, stream>>>(Hh, mW2, mb2, Th, MH, D_, DF_);
  }
  add_ln<<<dim3(NT), blk, 0, stream>>>(X, Vb, X, g4, b4);

  // ---- gated combine over experts + head, output transposed (B,PRED,C) ----
  combine_last<<<dim3(BB * CC), dim3(512), 0, stream>>>(X, gates, Qb);
  head_kernel<<<dim3(BB * CC), dim3(128), 0, stream>>>(Qb, hW, hb, out);
}

// Round 2
// 1365.528 us; speedup vs baseline: 5.1184x; 5.1184x over previous
//
#include <hip/hip_runtime.h>
#include <hip/hip_bf16.h>

#define NT   49152   // Ps*B*C*L tokens
#define D_   512
#define DF_  2048
#define PS   6
#define BB   16
#define CC   8
#define LL   64
#define PREDN 96

typedef unsigned short ushort_t;
using bf16x8 = __attribute__((ext_vector_type(8))) short;
using f32x4  = __attribute__((ext_vector_type(4))) float;

__device__ __forceinline__ float bf2f(unsigned short u) {
  return __uint_as_float((unsigned)u << 16);
}
__device__ __forceinline__ unsigned short f2bf(float f) {
  unsigned u = __float_as_uint(f);
  return (unsigned short)((u + 0x7fffu + ((u >> 16) & 1u)) >> 16);  // RNE
}
__device__ __forceinline__ void unp2(int x, float& a, float& b) {
  a = __uint_as_float((unsigned)x << 16);
  b = __uint_as_float((unsigned)x & 0xffff0000u);
}
__device__ __forceinline__ void gload16(const void* g, void* l) {
  __builtin_amdgcn_global_load_lds(
      (const __attribute__((address_space(1))) unsigned*)g,
      (__attribute__((address_space(3))) unsigned*)l, 16, 0, 0);
}

// ---------------------------------------------------------------------------
// bf16 MFMA GEMM (m97 structure): C[M,N] = A[M,K] @ Bt[N,K]^T + bias, bf16 out.
// BM=BN=128, BK=64, 256 threads (4 waves, 2x2), wave = 64x64 = 4x4 16x16 frags.
// M%128==0, N%128==0, K%64==0 (all call sites satisfy).
// ---------------------------------------------------------------------------
template <bool RELU>
__global__ __launch_bounds__(256) void gemm_mfma(
    const ushort_t* __restrict__ A,   // [M,K] bf16 row-major
    const ushort_t* __restrict__ Bt,  // [N,K] bf16 row-major (W^T)
    const float* __restrict__ bias,   // [N] f32
    ushort_t* __restrict__ C,         // [M,N] bf16
    int M, int N, int K) {
  __shared__ __align__(16) char smem[65536];
  short* Asm = (short*)smem;            // [2][128*64]
  short* Bsm = (short*)(smem + 32768);  // [2][128*64]
  const int tid = threadIdx.x;
  const int lane = tid & 63;
  const int w = tid >> 6;
  const int bm = blockIdx.x * 128;
  const int bn = blockIdx.y * 128;
  const int wr = (w >> 1) * 64;
  const int wc = (w & 1) * 64;
  f32x4 acc[4][4] = {};

  const int rowb = tid >> 3;
  const int kc = (tid & 7) << 3;

  auto stage = [&](int buf, int k0) {
#pragma unroll
    for (int it = 0; it < 4; ++it) {
      gload16(A + (size_t)(bm + it * 32 + rowb) * K + k0 + kc,
              Asm + buf * 8192 + it * 2048 + w * 512);
      gload16(Bt + (size_t)(bn + it * 32 + rowb) * K + k0 + kc,
              Bsm + buf * 8192 + it * 2048 + w * 512);
    }
  };
  auto compute = [&](int buf) {
    const short* ab = Asm + buf * 8192;
    const short* bb = Bsm + buf * 8192;
#pragma unroll
    for (int ks = 0; ks < 2; ++ks) {
      bf16x8 av[4], bv[4];
#pragma unroll
      for (int m = 0; m < 4; ++m)
        av[m] = *(const bf16x8*)(ab + (wr + m * 16 + (lane & 15)) * 64 + ks * 32 + (lane >> 4) * 8);
#pragma unroll
      for (int n = 0; n < 4; ++n)
        bv[n] = *(const bf16x8*)(bb + (wc + n * 16 + (lane & 15)) * 64 + ks * 32 + (lane >> 4) * 8);
#pragma unroll
      for (int m = 0; m < 4; ++m)
#pragma unroll
        for (int n = 0; n < 4; ++n)
          acc[m][n] = __builtin_amdgcn_mfma_f32_16x16x32_bf16(av[m], bv[n], acc[m][n], 0, 0, 0);
    }
  };

  const int nt = K >> 6;
  stage(0, 0);
  __syncthreads();
  for (int t = 0; t < nt; ++t) {
    if (t + 1 < nt) stage((t + 1) & 1, (t + 1) << 6);
    compute(t & 1);
    __syncthreads();
  }

  // Epilogue: acc -> LDS (f32, per-wave 64x64), then coalesced bf16x8 stores.
  float* Cs = (float*)smem;
  float* mc = Cs + (w << 12);
#pragma unroll
  for (int m = 0; m < 4; ++m)
#pragma unroll
    for (int n = 0; n < 4; ++n)
#pragma unroll
      for (int r = 0; r < 4; ++r)
        mc[(m * 16 + (lane >> 4) * 4 + r) * 64 + n * 16 + (lane & 15)] = acc[m][n][r];
  __syncthreads();
#pragma unroll
  for (int it = 0; it < 8; ++it) {
    int chunk = it * 256 + tid;        // 0..2047
    int r = chunk >> 4;                 // 0..127
    int cc2 = (chunk & 15) << 3;        // 0..120
    const float* src = Cs + ((r >> 6) * 2 + (cc2 >> 6)) * 4096 + (r & 63) * 64 + (cc2 & 63);
    int gn = bn + cc2;
    union { unsigned short u[8]; int4 v; } pk;
#pragma unroll
    for (int j = 0; j < 8; ++j) {
      float v = src[j] + bias[gn + j];
      if (RELU) v = fmaxf(v, 0.f);
      pk.u[j] = f2bf(v);
    }
    *(int4*)(C + (size_t)(bm + r) * N + gn) = pk.v;
  }
}

// ---------------------------------------------------------------------------
// Weight prep: Wt[n][k] = bf16(W[k][n]).  grid (K/32, N/32), 256 threads.
// ---------------------------------------------------------------------------
__global__ __launch_bounds__(256) void transpose_bf16(
    const float* __restrict__ W, ushort_t* __restrict__ Wt, int K, int N) {
  __shared__ float tile[32][33];
  const int k0 = blockIdx.x * 32, n0 = blockIdx.y * 32;
  const int tx = threadIdx.x & 31, ty = threadIdx.x >> 5;
#pragma unroll
  for (int i = 0; i < 4; ++i)
    tile[ty + i * 8][tx] = W[(size_t)(k0 + ty + i * 8) * N + n0 + tx];
  __syncthreads();
#pragma unroll
  for (int i = 0; i < 4; ++i)
    Wt[(size_t)(n0 + ty + i * 8) * K + k0 + tx] = f2bf(tile[tx][ty + i * 8]);
}

__global__ __launch_bounds__(256) void conv_bf16(
    const float* __restrict__ in, ushort_t* __restrict__ out, int n8) {
  int i = blockIdx.x * 256 + threadIdx.x;
  if (i >= n8) return;
  const float4* p = (const float4*)in + (size_t)i * 2;
  float4 a = p[0], b = p[1];
  union { unsigned short u[8]; int4 v; } pk;
  pk.u[0] = f2bf(a.x); pk.u[1] = f2bf(a.y); pk.u[2] = f2bf(a.z); pk.u[3] = f2bf(a.w);
  pk.u[4] = f2bf(b.x); pk.u[5] = f2bf(b.y); pk.u[6] = f2bf(b.z); pk.u[7] = f2bf(b.w);
  ((int4*)out)[i] = pk.v;
}

// ---------------------------------------------------------------------------
// Attention over sequence axis (S=64, dh=64), bf16 I/O, f32 LDS math.
// O may alias Q (all reads staged before writes; blocks disjoint).
// ---------------------------------------------------------------------------
__global__ __launch_bounds__(256) void attn_seq(
    const ushort_t* __restrict__ Q, const ushort_t* __restrict__ K,
    const ushort_t* __restrict__ V, ushort_t* O) {
  __shared__ float qs[64][65], ks[64][65], vs[64][64];
  const int h = blockIdx.x & 7;
  const int g = blockIdx.x >> 3;
  const size_t base = (size_t)g * 64 * D_ + h * 64;
  const int tid = threadIdx.x;
#pragma unroll
  for (int it = 0; it < 2; ++it) {
    int c = it * 256 + tid;  // 0..511
    int l = c >> 3, dc = (c & 7) * 8;
    size_t idx = base + (size_t)l * D_ + dc;
    int4 qv = *(const int4*)(Q + idx);
    int4 kv = *(const int4*)(K + idx);
    int4 vv = *(const int4*)(V + idx);
    unp2(qv.x, qs[l][dc + 0], qs[l][dc + 1]); unp2(qv.y, qs[l][dc + 2], qs[l][dc + 3]);
    unp2(qv.z, qs[l][dc + 4], qs[l][dc + 5]); unp2(qv.w, qs[l][dc + 6], qs[l][dc + 7]);
    unp2(kv.x, ks[l][dc + 0], ks[l][dc + 1]); unp2(kv.y, ks[l][dc + 2], ks[l][dc + 3]);
    unp2(kv.z, ks[l][dc + 4], ks[l][dc + 5]); unp2(kv.w, ks[l][dc + 6], ks[l][dc + 7]);
    unp2(vv.x, vs[l][dc + 0], vs[l][dc + 1]); unp2(vv.y, vs[l][dc + 2], vs[l][dc + 3]);
    unp2(vv.z, vs[l][dc + 4], vs[l][dc + 5]); unp2(vv.w, vs[l][dc + 6], vs[l][dc + 7]);
  }
  __syncthreads();
  float sc[16];
#pragma unroll
  for (int j = 0; j < 16; ++j) {
    int e = tid + j * 256;
    int i = e >> 6, t = e & 63;
    float s = 0.f;
#pragma unroll
    for (int d = 0; d < 64; ++d) s += qs[i][d] * ks[t][d];
    sc[j] = s * 0.125f;
  }
  __syncthreads();
#pragma unroll
  for (int j = 0; j < 16; ++j) {
    int e = tid + j * 256;
    qs[e >> 6][e & 63] = sc[j];
  }
  __syncthreads();
  if (tid < 64) {
    float mx = -1e30f;
#pragma unroll
    for (int t = 0; t < 64; ++t) mx = fmaxf(mx, qs[tid][t]);
    float sum = 0.f;
#pragma unroll
    for (int t = 0; t < 64; ++t) { float e = __expf(qs[tid][t] - mx); qs[tid][t] = e; sum += e; }
    float inv = 1.f / sum;
#pragma unroll
    for (int t = 0; t < 64; ++t) qs[tid][t] *= inv;
  }
  __syncthreads();
#pragma unroll
  for (int j = 0; j < 16; ++j) {
    int e = tid + j * 256;
    int i = e >> 6, d = e & 63;
    float s = 0.f;
#pragma unroll
    for (int t = 0; t < 64; ++t) s += qs[i][t] * vs[t][d];
    O[base + (size_t)i * D_ + d] = f2bf(s);
  }
}

// ---------------------------------------------------------------------------
// Attention over context axis (S=8, dh=64), bf16 I/O.
// ---------------------------------------------------------------------------
__global__ __launch_bounds__(64) void attn_ctx(
    const ushort_t* __restrict__ Q, const ushort_t* __restrict__ K,
    const ushort_t* __restrict__ V, ushort_t* O) {
  __shared__ float qs[8][65], ks[8][65], vs[8][65], ps[8][9];
  const int h = blockIdx.x & 7;
  const int l = (blockIdx.x >> 3) & 63;
  const int pb = blockIdx.x >> 9;
  const size_t row0 = (size_t)pb * 512 + l;
  const int tid = threadIdx.x;
#pragma unroll
  for (int c = 0; c < 8; ++c) {
    size_t idx = (row0 + (size_t)c * 64) * D_ + h * 64 + tid;
    qs[c][tid] = bf2f(Q[idx]);
    ks[c][tid] = bf2f(K[idx]);
    vs[c][tid] = bf2f(V[idx]);
  }
  __syncthreads();
  {
    int i = tid >> 3, t = tid & 7;
    float s = 0.f;
#pragma unroll
    for (int d = 0; d < 64; ++d) s += qs[i][d] * ks[t][d];
    ps[i][t] = s * 0.125f;
  }
  __syncthreads();
  if (tid < 8) {
    float mx = -1e30f;
#pragma unroll
    for (int t = 0; t < 8; ++t) mx = fmaxf(mx, ps[tid][t]);
    float sum = 0.f;
#pragma unroll
    for (int t = 0; t < 8; ++t) { float e = __expf(ps[tid][t] - mx); ps[tid][t] = e; sum += e; }
    float inv = 1.f / sum;
#pragma unroll
    for (int t = 0; t < 8; ++t) ps[tid][t] *= inv;
  }
  __syncthreads();
#pragma unroll
  for (int c = 0; c < 8; ++c) {
    float s = 0.f;
#pragma unroll
    for (int t = 0; t < 8; ++t) s += ps[c][t] * vs[t][tid];
    O[(row0 + (size_t)c * 64) * D_ + h * 64 + tid] = f2bf(s);
  }
}

// ---------------------------------------------------------------------------
// Xout(f32) = LN(Xin + T) * g + b ; optional bf16 copy Xbf of the LN output.
// T may alias Xbf (per-thread read-before-write). NO restrict on T/Xbf.
// ---------------------------------------------------------------------------
__global__ __launch_bounds__(256) void add_ln(
    const float* __restrict__ Xin, const ushort_t* T, float* Xout, ushort_t* Xbf,
    const float* __restrict__ g, const float* __restrict__ b) {
  const size_t off = (size_t)blockIdx.x * D_;
  const int tid = threadIdx.x;
  float x0 = Xin[off + tid] + bf2f(T[off + tid]);
  float x1 = Xin[off + tid + 256] + bf2f(T[off + tid + 256]);
  float s = x0 + x1, q = x0 * x0 + x1 * x1;
#pragma unroll
  for (int o = 32; o > 0; o >>= 1) { s += __shfl_down(s, o); q += __shfl_down(q, o); }
  __shared__ float ssum[4], sqsum[4];
  if ((tid & 63) == 0) { ssum[tid >> 6] = s; sqsum[tid >> 6] = q; }
  __syncthreads();
  float S = ssum[0] + ssum[1] + ssum[2] + ssum[3];
  float Qs = sqsum[0] + sqsum[1] + sqsum[2] + sqsum[3];
  float m = S * (1.f / D_);
  float var = Qs * (1.f / D_) - m * m;
  float inv = rsqrtf(var + 1e-5f);
  float y0 = (x0 - m) * inv * g[tid] + b[tid];
  float y1 = (x1 - m) * inv * g[tid + 256] + b[tid + 256];
  Xout[off + tid] = y0;
  Xout[off + tid + 256] = y1;
  if (Xbf) { Xbf[off + tid] = f2bf(y0); Xbf[off + tid + 256] = f2bf(y1); }
}

__global__ __launch_bounds__(512) void combine_last(
    const float* __restrict__ X, const float* __restrict__ gates,
    float* __restrict__ comb) {
  const int b = blockIdx.x >> 3, c = blockIdx.x & 7;
  const int d = threadIdx.x;
  float s = 0.f;
#pragma unroll
  for (int p = 0; p < PS; ++p) {
    size_t row = ((size_t)(p * BB + b) * CC + c) * LL + (LL - 1);
    s += gates[b * PS + p] * X[row * D_ + d];
  }
  comb[(size_t)blockIdx.x * D_ + d] = s;
}

__global__ __launch_bounds__(128) void head_kernel(
    const float* __restrict__ comb, const float* __restrict__ hW,
    const float* __restrict__ hb, float* __restrict__ out) {
  __shared__ float xr[D_];
  const int bc = blockIdx.x;
  for (int i = threadIdx.x; i < D_; i += 128) xr[i] = comb[(size_t)bc * D_ + i];
  __syncthreads();
  const int n = threadIdx.x;
  if (n < PREDN) {
    float s = hb[n];
    for (int d = 0; d < D_; ++d) s += xr[d] * hW[d * PREDN + n];
    const int b = bc >> 3, c = bc & 7;
    out[((size_t)b * PREDN + n) * CC + c] = s;
  }
}

// ---------------------------------------------------------------------------
extern "C" void kernel_launch(void* const* d_in, const int* in_sizes, int n_in,
                              void* d_out, int out_size, void* d_ws, size_t ws_size,
                              hipStream_t stream) {
  const float* ex    = (const float*)d_in[0];
  const float* gates = (const float*)d_in[1];
  const float* cWq = (const float*)d_in[2];  const float* cbq = (const float*)d_in[3];
  const float* cWk = (const float*)d_in[4];  const float* cbk = (const float*)d_in[5];
  const float* cWv = (const float*)d_in[6];  const float* cbv = (const float*)d_in[7];
  const float* cWo = (const float*)d_in[8];  const float* cbo = (const float*)d_in[9];
  const float* iWq = (const float*)d_in[10]; const float* ibq = (const float*)d_in[11];
  const float* iWk = (const float*)d_in[12]; const float* ibk = (const float*)d_in[13];
  const float* iWv = (const float*)d_in[14]; const float* ibv = (const float*)d_in[15];
  const float* iWo = (const float*)d_in[16]; const float* ibo = (const float*)d_in[17];
  const float* mW1 = (const float*)d_in[18]; const float* mb1 = (const float*)d_in[19];
  const float* mW2 = (const float*)d_in[20]; const float* mb2 = (const float*)d_in[21];
  const float* g1  = (const float*)d_in[22]; const float* b1  = (const float*)d_in[23];
  const float* g3  = (const float*)d_in[24]; const float* b3  = (const float*)d_in[25];
  const float* g4  = (const float*)d_in[26]; const float* b4  = (const float*)d_in[27];
  const float* hW  = (const float*)d_in[28]; const float* hb  = (const float*)d_in[29];
  float* out = (float*)d_out;

  // ---- workspace layout ----
  // weights (bf16 W^T): 8x 512*512 + 2048*512 + 512*2048 = 4M shorts = 8 MB
  ushort_t* wq  = (ushort_t*)d_ws;
  ushort_t* wk  = wq  + 262144;
  ushort_t* wv  = wk  + 262144;
  ushort_t* wo  = wv  + 262144;
  ushort_t* wiq = wo  + 262144;
  ushort_t* wik = wiq + 262144;
  ushort_t* wiv = wik + 262144;
  ushort_t* wio = wiv + 262144;
  ushort_t* w1  = wio + 262144;           // [2048][512]
  ushort_t* w2  = w1  + 1048576;          // [512][2048]
  float*    Xf  = (float*)(w2 + 1048576); // residual stream f32, NT*512
  ushort_t* Xb  = (ushort_t*)(Xf + (size_t)NT * D_);  // bf16 activations
  ushort_t* Qb  = Xb + (size_t)NT * D_;
  ushort_t* Kb  = Qb + (size_t)NT * D_;
  ushort_t* Vb  = Kb + (size_t)NT * D_;
  ushort_t* Tb  = Vb + (size_t)NT * D_;
  float*   comb = (float*)(Tb + (size_t)NT * D_);  // 128*512 f32

  // ---- weight prep ----
  transpose_bf16<<<dim3(16, 16), 256, 0, stream>>>(cWq, wq, 512, 512);
  transpose_bf16<<<dim3(16, 16), 256, 0, stream>>>(cWk, wk, 512, 512);
  transpose_bf16<<<dim3(16, 16), 256, 0, stream>>>(cWv, wv, 512, 512);
  transpose_bf16<<<dim3(16, 16), 256, 0, stream>>>(cWo, wo, 512, 512);
  transpose_bf16<<<dim3(16, 16), 256, 0, stream>>>(iWq, wiq, 512, 512);
  transpose_bf16<<<dim3(16, 16), 256, 0, stream>>>(iWk, wik, 512, 512);
  transpose_bf16<<<dim3(16, 16), 256, 0, stream>>>(iWv, wiv, 512, 512);
  transpose_bf16<<<dim3(16, 16), 256, 0, stream>>>(iWo, wio, 512, 512);
  transpose_bf16<<<dim3(16, 64), 256, 0, stream>>>(mW1, w1, 512, 2048);
  transpose_bf16<<<dim3(64, 16), 256, 0, stream>>>(mW2, w2, 2048, 512);
  conv_bf16<<<dim3(NT * D_ / 8 / 256), 256, 0, stream>>>(ex, Xb, NT * D_ / 8);

  dim3 blk(256);
  dim3 g512(NT / 128, 4);

  // ---- block 1: cross attention (over L) ----
  gemm_mfma<false><<<g512, blk, 0, stream>>>(Xb, wq, cbq, Qb, NT, 512, 512);
  gemm_mfma<false><<<g512, blk, 0, stream>>>(Xb, wk, cbk, Kb, NT, 512, 512);
  gemm_mfma<false><<<g512, blk, 0, stream>>>(Xb, wv, cbv, Vb, NT, 512, 512);
  attn_seq<<<dim3(768 * 8), blk, 0, stream>>>(Qb, Kb, Vb, Qb);
  gemm_mfma<false><<<g512, blk, 0, stream>>>(Qb, wo, cbo, Tb, NT, 512, 512);
  add_ln<<<dim3(NT), blk, 0, stream>>>(ex, Tb, Xf, Xb, g1, b1);

  // ---- block 2: inner attention (over C) ----
  gemm_mfma<false><<<g512, blk, 0, stream>>>(Xb, wiq, ibq, Qb, NT, 512, 512);
  gemm_mfma<false><<<g512, blk, 0, stream>>>(Xb, wik, ibk, Kb, NT, 512, 512);
  gemm_mfma<false><<<g512, blk, 0, stream>>>(Xb, wiv, ibv, Vb, NT, 512, 512);
  attn_ctx<<<dim3(NT), dim3(64), 0, stream>>>(Qb, Kb, Vb, Qb);
  gemm_mfma<false><<<g512, blk, 0, stream>>>(Qb, wio, ibo, Tb, NT, 512, 512);
  add_ln<<<dim3(NT), blk, 0, stream>>>(Xf, Tb, Xf, Xb, g3, b3);

  // ---- MLP: hidden H (bf16, NT*2048 = 201 MB) overlays Qb..Tb exactly ----
  gemm_mfma<true ><<<dim3(NT / 128, 16), blk, 0, stream>>>(Xb, w1, mb1, Qb, NT, 2048, 512);
  gemm_mfma<false><<<dim3(NT / 128, 4),  blk, 0, stream>>>(Qb, w2, mb2, Xb, NT, 512, 2048);
  add_ln<<<dim3(NT), blk, 0, stream>>>(Xf, Xb, Xf, (ushort_t*)nullptr, g4, b4);

  // ---- gated combine + head ----
  combine_last<<<dim3(BB * CC), dim3(512), 0, stream>>>(Xf, gates, comb);
  head_kernel<<<dim3(BB * CC), dim3(128), 0, stream>>>(comb, hW, hb, out);
}

// Round 3
// 1023.508 us; speedup vs baseline: 6.8288x; 1.3342x over previous
//
#include <hip/hip_runtime.h>
#include <hip/hip_bf16.h>

#define NT   49152   // Ps*B*C*L tokens
#define D_   512
#define DF_  2048
#define PS   6
#define BB   16
#define CC   8
#define LL   64
#define PREDN 96

typedef unsigned short ushort_t;
using bf16x8 = __attribute__((ext_vector_type(8))) short;
using f32x4  = __attribute__((ext_vector_type(4))) float;

__device__ __forceinline__ float bf2f(unsigned short u) {
  return __uint_as_float((unsigned)u << 16);
}
__device__ __forceinline__ unsigned short f2bf(float f) {
  unsigned u = __float_as_uint(f);
  return (unsigned short)((u + 0x7fffu + ((u >> 16) & 1u)) >> 16);  // RNE
}
__device__ __forceinline__ void unp2(int x, float& a, float& b) {
  a = __uint_as_float((unsigned)x << 16);
  b = __uint_as_float((unsigned)x & 0xffff0000u);
}
__device__ __forceinline__ void gload16(const void* g, void* l) {
  __builtin_amdgcn_global_load_lds(
      (const __attribute__((address_space(1))) unsigned*)g,
      (__attribute__((address_space(3))) unsigned*)l, 16, 0, 0);
}

// ---------------------------------------------------------------------------
// bf16 MFMA GEMM: C[M,N] = A[M,K] @ Bt[N,K]^T + bias, bf16 out.
// BM=BN=128, BK=64, 256 threads (4 waves, 2x2), wave = 64x64 = 4x4 16x16 frags.
// ROWBIAS: bias indexed by m (used for the transposed-V projection).
// ---------------------------------------------------------------------------
template <bool RELU, bool ROWBIAS>
__global__ __launch_bounds__(256) void gemm_mfma(
    const ushort_t* __restrict__ A,   // [M,K] bf16 row-major
    const ushort_t* __restrict__ Bt,  // [N,K] bf16 row-major
    const float* __restrict__ bias,
    ushort_t* __restrict__ C,         // [M,N] bf16
    int M, int N, int K) {
  __shared__ __align__(16) char smem[65536];
  short* Asm = (short*)smem;            // [2][128*64]
  short* Bsm = (short*)(smem + 32768);  // [2][128*64]
  const int tid = threadIdx.x;
  const int lane = tid & 63;
  const int w = tid >> 6;
  const int bm = blockIdx.x * 128;
  const int bn = blockIdx.y * 128;
  const int wr = (w >> 1) * 64;
  const int wc = (w & 1) * 64;
  f32x4 acc[4][4] = {};

  const int rowb = tid >> 3;
  const int kc = (tid & 7) << 3;

  auto stage = [&](int buf, int k0) {
#pragma unroll
    for (int it = 0; it < 4; ++it) {
      gload16(A + (size_t)(bm + it * 32 + rowb) * K + k0 + kc,
              Asm + buf * 8192 + it * 2048 + w * 512);
      gload16(Bt + (size_t)(bn + it * 32 + rowb) * K + k0 + kc,
              Bsm + buf * 8192 + it * 2048 + w * 512);
    }
  };
  auto compute = [&](int buf) {
    const short* ab = Asm + buf * 8192;
    const short* bb = Bsm + buf * 8192;
#pragma unroll
    for (int ks = 0; ks < 2; ++ks) {
      bf16x8 av[4], bv[4];
#pragma unroll
      for (int m = 0; m < 4; ++m)
        av[m] = *(const bf16x8*)(ab + (wr + m * 16 + (lane & 15)) * 64 + ks * 32 + (lane >> 4) * 8);
#pragma unroll
      for (int n = 0; n < 4; ++n)
        bv[n] = *(const bf16x8*)(bb + (wc + n * 16 + (lane & 15)) * 64 + ks * 32 + (lane >> 4) * 8);
#pragma unroll
      for (int m = 0; m < 4; ++m)
#pragma unroll
        for (int n = 0; n < 4; ++n)
          acc[m][n] = __builtin_amdgcn_mfma_f32_16x16x32_bf16(av[m], bv[n], acc[m][n], 0, 0, 0);
    }
  };

  const int nt = K >> 6;
  stage(0, 0);
  __syncthreads();
  for (int t = 0; t < nt; ++t) {
    if (t + 1 < nt) stage((t + 1) & 1, (t + 1) << 6);
    compute(t & 1);
    __syncthreads();
  }

  // Epilogue: acc -> LDS (f32, per-wave 64x64), then coalesced bf16x8 stores.
  float* Cs = (float*)smem;
  float* mc = Cs + (w << 12);
#pragma unroll
  for (int m = 0; m < 4; ++m)
#pragma unroll
    for (int n = 0; n < 4; ++n)
#pragma unroll
      for (int r = 0; r < 4; ++r)
        mc[(m * 16 + (lane >> 4) * 4 + r) * 64 + n * 16 + (lane & 15)] = acc[m][n][r];
  __syncthreads();
#pragma unroll
  for (int it = 0; it < 8; ++it) {
    int chunk = it * 256 + tid;        // 0..2047
    int r = chunk >> 4;                 // 0..127
    int cc2 = (chunk & 15) << 3;        // 0..120
    const float* src = Cs + ((r >> 6) * 2 + (cc2 >> 6)) * 4096 + (r & 63) * 64 + (cc2 & 63);
    int gn = bn + cc2;
    union { unsigned short u[8]; int4 v; } pk;
#pragma unroll
    for (int j = 0; j < 8; ++j) {
      float v = src[j] + (ROWBIAS ? bias[bm + r] : bias[gn + j]);
      if (RELU) v = fmaxf(v, 0.f);
      pk.u[j] = f2bf(v);
    }
    *(int4*)(C + (size_t)(bm + r) * N + gn) = pk.v;
  }
}

// ---------------------------------------------------------------------------
__global__ __launch_bounds__(256) void transpose_bf16(
    const float* __restrict__ W, ushort_t* __restrict__ Wt, int K, int N) {
  __shared__ float tile[32][33];
  const int k0 = blockIdx.x * 32, n0 = blockIdx.y * 32;
  const int tx = threadIdx.x & 31, ty = threadIdx.x >> 5;
#pragma unroll
  for (int i = 0; i < 4; ++i)
    tile[ty + i * 8][tx] = W[(size_t)(k0 + ty + i * 8) * N + n0 + tx];
  __syncthreads();
#pragma unroll
  for (int i = 0; i < 4; ++i)
    Wt[(size_t)(n0 + ty + i * 8) * K + k0 + tx] = f2bf(tile[tx][ty + i * 8]);
}

__global__ __launch_bounds__(256) void conv_bf16(
    const float* __restrict__ in, ushort_t* __restrict__ out, int n8) {
  int i = blockIdx.x * 256 + threadIdx.x;
  if (i >= n8) return;
  const float4* p = (const float4*)in + (size_t)i * 2;
  float4 a = p[0], b = p[1];
  union { unsigned short u[8]; int4 v; } pk;
  pk.u[0] = f2bf(a.x); pk.u[1] = f2bf(a.y); pk.u[2] = f2bf(a.z); pk.u[3] = f2bf(a.w);
  pk.u[4] = f2bf(b.x); pk.u[5] = f2bf(b.y); pk.u[6] = f2bf(b.z); pk.u[7] = f2bf(b.w);
  ((int4*)out)[i] = pk.v;
}

// ---------------------------------------------------------------------------
// MFMA attention over sequence axis (S=64, dh=64). One block per (group,head).
// QK: [NT][1024] fused Q|K. Vt: [512][NT] transposed V. O: [NT][512].
// ---------------------------------------------------------------------------
__global__ __launch_bounds__(256) void attn_seq_mfma(
    const ushort_t* __restrict__ QK, const ushort_t* __restrict__ Vt,
    ushort_t* __restrict__ O) {
  __shared__ __align__(16) char smem[27648];
  short* qs = (short*)smem;            // [64][72] bf16; later P; later O
  short* ks = (short*)(smem + 9216);   // [64][72] bf16
  short* vt = (short*)(smem + 18432);  // [64][72] bf16 (V^T tile: [d][t])
  float* S  = (float*)smem;            // [64][66] f32 (overlays qs+ks)
  const int h = blockIdx.x & 7;
  const int g = blockIdx.x >> 3;
  const int tid = threadIdx.x;
  const int lane = tid & 63;
  const int w = tid >> 6;
  const int wr = (w >> 1) * 32, wc = (w & 1) * 32;

  {
    const size_t qkbase = (size_t)g * 64 * 1024 + h * 64;
    const size_t vbase  = (size_t)(h * 64) * NT + (size_t)g * 64;
#pragma unroll
    for (int it = 0; it < 2; ++it) {
      int t = it * 256 + tid;            // 0..511
      int r = t >> 3, c = (t & 7) * 8;
      int4 qv = *(const int4*)(QK + qkbase + (size_t)r * 1024 + c);
      int4 kv = *(const int4*)(QK + qkbase + (size_t)r * 1024 + 512 + c);
      int4 vv = *(const int4*)(Vt + vbase + (size_t)r * NT + c);
      *(int4*)(qs + r * 72 + c) = qv;
      *(int4*)(ks + r * 72 + c) = kv;
      *(int4*)(vt + r * 72 + c) = vv;
    }
  }
  __syncthreads();

  // S = Q K^T (raw; scale folded into softmax)
  f32x4 acc[2][2] = {};
#pragma unroll
  for (int k2 = 0; k2 < 2; ++k2) {
    bf16x8 aq[2], bk[2];
#pragma unroll
    for (int m = 0; m < 2; ++m)
      aq[m] = *(const bf16x8*)(qs + (wr + m * 16 + (lane & 15)) * 72 + k2 * 32 + (lane >> 4) * 8);
#pragma unroll
    for (int n = 0; n < 2; ++n)
      bk[n] = *(const bf16x8*)(ks + (wc + n * 16 + (lane & 15)) * 72 + k2 * 32 + (lane >> 4) * 8);
#pragma unroll
    for (int m = 0; m < 2; ++m)
#pragma unroll
      for (int n = 0; n < 2; ++n)
        acc[m][n] = __builtin_amdgcn_mfma_f32_16x16x32_bf16(aq[m], bk[n], acc[m][n], 0, 0, 0);
  }
  __syncthreads();
#pragma unroll
  for (int m = 0; m < 2; ++m)
#pragma unroll
    for (int n = 0; n < 2; ++n)
#pragma unroll
      for (int r = 0; r < 4; ++r)
        S[(wr + m * 16 + (lane >> 4) * 4 + r) * 66 + wc + n * 16 + (lane & 15)] = acc[m][n][r];
  __syncthreads();

  // wave-parallel softmax: 4 lanes per row, 16 cols each
  {
    int row = tid >> 2, q = tid & 3;
    float v[16];
    float mx = -1e30f;
#pragma unroll
    for (int j = 0; j < 16; ++j) { v[j] = S[row * 66 + q * 16 + j]; mx = fmaxf(mx, v[j]); }
    mx = fmaxf(mx, __shfl_xor(mx, 1));
    mx = fmaxf(mx, __shfl_xor(mx, 2));
    float sum = 0.f;
#pragma unroll
    for (int j = 0; j < 16; ++j) { v[j] = __expf((v[j] - mx) * 0.125f); sum += v[j]; }
    sum += __shfl_xor(sum, 1);
    sum += __shfl_xor(sum, 2);
    float inv = 1.f / sum;
    __syncthreads();   // all S reads complete before P overwrites the region
    union { unsigned short u[16]; int4 i4[2]; } pk;
#pragma unroll
    for (int j = 0; j < 16; ++j) pk.u[j] = f2bf(v[j] * inv);
    *(int4*)(qs + row * 72 + q * 16) = pk.i4[0];
    *(int4*)(qs + row * 72 + q * 16 + 8) = pk.i4[1];
  }
  __syncthreads();

  // O = P V  (A = P rows, B = vt rows = V columns)
  f32x4 acc2[2][2] = {};
#pragma unroll
  for (int k2 = 0; k2 < 2; ++k2) {
    bf16x8 ap[2], bv[2];
#pragma unroll
    for (int m = 0; m < 2; ++m)
      ap[m] = *(const bf16x8*)(qs + (wr + m * 16 + (lane & 15)) * 72 + k2 * 32 + (lane >> 4) * 8);
#pragma unroll
    for (int n = 0; n < 2; ++n)
      bv[n] = *(const bf16x8*)(vt + (wc + n * 16 + (lane & 15)) * 72 + k2 * 32 + (lane >> 4) * 8);
#pragma unroll
    for (int m = 0; m < 2; ++m)
#pragma unroll
      for (int n = 0; n < 2; ++n)
        acc2[m][n] = __builtin_amdgcn_mfma_f32_16x16x32_bf16(ap[m], bv[n], acc2[m][n], 0, 0, 0);
  }
  __syncthreads();
  short* Os = qs;   // reuse as bf16 [64][72]
#pragma unroll
  for (int m = 0; m < 2; ++m)
#pragma unroll
    for (int n = 0; n < 2; ++n)
#pragma unroll
      for (int r = 0; r < 4; ++r)
        Os[(wr + m * 16 + (lane >> 4) * 4 + r) * 72 + wc + n * 16 + (lane & 15)] = f2bf(acc2[m][n][r]);
  __syncthreads();
#pragma unroll
  for (int it = 0; it < 2; ++it) {
    int t = it * 256 + tid;
    int r = t >> 3, c = (t & 7) * 8;
    *(int4*)(O + (size_t)(g * 64 + r) * 512 + h * 64 + c) = *(const int4*)(Os + r * 72 + c);
  }
}

// ---------------------------------------------------------------------------
// Attention over context axis (S=8, dh=64): vectorized loads, f32 LDS math.
// QK: [NT][1024] fused. V: [NT][512]. O: [NT][512].
// ---------------------------------------------------------------------------
__global__ __launch_bounds__(64) void attn_ctx(
    const ushort_t* __restrict__ QK, const ushort_t* __restrict__ V,
    ushort_t* __restrict__ O) {
  __shared__ float qs[8][72], ks[8][72], vs[8][72], ps[8][9];
  const int h = blockIdx.x & 7;
  const int l = (blockIdx.x >> 3) & 63;
  const int pb = blockIdx.x >> 9;
  const size_t row0 = (size_t)pb * 512 + l;
  const int tid = threadIdx.x;
  {
    int c = tid >> 3, dc = (tid & 7) * 8;
    size_t r = row0 + (size_t)c * 64;
    int4 qv = *(const int4*)(QK + r * 1024 + h * 64 + dc);
    int4 kv = *(const int4*)(QK + r * 1024 + 512 + h * 64 + dc);
    int4 vv = *(const int4*)(V + r * 512 + h * 64 + dc);
    unp2(qv.x, qs[c][dc + 0], qs[c][dc + 1]); unp2(qv.y, qs[c][dc + 2], qs[c][dc + 3]);
    unp2(qv.z, qs[c][dc + 4], qs[c][dc + 5]); unp2(qv.w, qs[c][dc + 6], qs[c][dc + 7]);
    unp2(kv.x, ks[c][dc + 0], ks[c][dc + 1]); unp2(kv.y, ks[c][dc + 2], ks[c][dc + 3]);
    unp2(kv.z, ks[c][dc + 4], ks[c][dc + 5]); unp2(kv.w, ks[c][dc + 6], ks[c][dc + 7]);
    unp2(vv.x, vs[c][dc + 0], vs[c][dc + 1]); unp2(vv.y, vs[c][dc + 2], vs[c][dc + 3]);
    unp2(vv.z, vs[c][dc + 4], vs[c][dc + 5]); unp2(vv.w, vs[c][dc + 6], vs[c][dc + 7]);
  }
  __syncthreads();
  {
    int i = tid >> 3, t = tid & 7;
    float s = 0.f;
#pragma unroll
    for (int d = 0; d < 64; ++d) s += qs[i][d] * ks[t][d];
    ps[i][t] = s * 0.125f;
  }
  __syncthreads();
  if (tid < 8) {
    float mx = -1e30f;
#pragma unroll
    for (int t = 0; t < 8; ++t) mx = fmaxf(mx, ps[tid][t]);
    float sum = 0.f;
#pragma unroll
    for (int t = 0; t < 8; ++t) { float e = __expf(ps[tid][t] - mx); ps[tid][t] = e; sum += e; }
    float inv = 1.f / sum;
#pragma unroll
    for (int t = 0; t < 8; ++t) ps[tid][t] *= inv;
  }
  __syncthreads();
#pragma unroll
  for (int c = 0; c < 8; ++c) {
    float s = 0.f;
#pragma unroll
    for (int t = 0; t < 8; ++t) s += ps[c][t] * vs[t][tid];
    O[(row0 + (size_t)c * 64) * D_ + h * 64 + tid] = f2bf(s);
  }
}

// ---------------------------------------------------------------------------
__global__ __launch_bounds__(256) void add_ln(
    const float* __restrict__ Xin, const ushort_t* T, float* Xout, ushort_t* Xbf,
    const float* __restrict__ g, const float* __restrict__ b) {
  const size_t off = (size_t)blockIdx.x * D_;
  const int tid = threadIdx.x;
  float x0 = Xin[off + tid] + bf2f(T[off + tid]);
  float x1 = Xin[off + tid + 256] + bf2f(T[off + tid + 256]);
  float s = x0 + x1, q = x0 * x0 + x1 * x1;
#pragma unroll
  for (int o = 32; o > 0; o >>= 1) { s += __shfl_down(s, o); q += __shfl_down(q, o); }
  __shared__ float ssum[4], sqsum[4];
  if ((tid & 63) == 0) { ssum[tid >> 6] = s; sqsum[tid >> 6] = q; }
  __syncthreads();
  float S = ssum[0] + ssum[1] + ssum[2] + ssum[3];
  float Qs = sqsum[0] + sqsum[1] + sqsum[2] + sqsum[3];
  float m = S * (1.f / D_);
  float var = Qs * (1.f / D_) - m * m;
  float inv = rsqrtf(var + 1e-5f);
  float y0 = (x0 - m) * inv * g[tid] + b[tid];
  float y1 = (x1 - m) * inv * g[tid + 256] + b[tid + 256];
  Xout[off + tid] = y0;
  Xout[off + tid + 256] = y1;
  if (Xbf) { Xbf[off + tid] = f2bf(y0); Xbf[off + tid + 256] = f2bf(y1); }
}

__global__ __launch_bounds__(512) void combine_last(
    const float* __restrict__ X, const float* __restrict__ gates,
    float* __restrict__ comb) {
  const int b = blockIdx.x >> 3, c = blockIdx.x & 7;
  const int d = threadIdx.x;
  float s = 0.f;
#pragma unroll
  for (int p = 0; p < PS; ++p) {
    size_t row = ((size_t)(p * BB + b) * CC + c) * LL + (LL - 1);
    s += gates[b * PS + p] * X[row * D_ + d];
  }
  comb[(size_t)blockIdx.x * D_ + d] = s;
}

__global__ __launch_bounds__(128) void head_kernel(
    const float* __restrict__ comb, const float* __restrict__ hW,
    const float* __restrict__ hb, float* __restrict__ out) {
  __shared__ float xr[D_];
  const int bc = blockIdx.x;
  for (int i = threadIdx.x; i < D_; i += 128) xr[i] = comb[(size_t)bc * D_ + i];
  __syncthreads();
  const int n = threadIdx.x;
  if (n < PREDN) {
    float s = hb[n];
    for (int d = 0; d < D_; ++d) s += xr[d] * hW[d * PREDN + n];
    const int b = bc >> 3, c = bc & 7;
    out[((size_t)b * PREDN + n) * CC + c] = s;
  }
}

// ---------------------------------------------------------------------------
extern "C" void kernel_launch(void* const* d_in, const int* in_sizes, int n_in,
                              void* d_out, int out_size, void* d_ws, size_t ws_size,
                              hipStream_t stream) {
  const float* ex    = (const float*)d_in[0];
  const float* gates = (const float*)d_in[1];
  const float* cWq = (const float*)d_in[2];  const float* cbq = (const float*)d_in[3];
  const float* cWk = (const float*)d_in[4];  const float* cbk = (const float*)d_in[5];
  const float* cWv = (const float*)d_in[6];  const float* cbv = (const float*)d_in[7];
  const float* cWo = (const float*)d_in[8];  const float* cbo = (const float*)d_in[9];
  const float* iWq = (const float*)d_in[10]; const float* ibq = (const float*)d_in[11];
  const float* iWk = (const float*)d_in[12]; const float* ibk = (const float*)d_in[13];
  const float* iWv = (const float*)d_in[14]; const float* ibv = (const float*)d_in[15];
  const float* iWo = (const float*)d_in[16]; const float* ibo = (const float*)d_in[17];
  const float* mW1 = (const float*)d_in[18]; const float* mb1 = (const float*)d_in[19];
  const float* mW2 = (const float*)d_in[20]; const float* mb2 = (const float*)d_in[21];
  const float* g1  = (const float*)d_in[22]; const float* b1  = (const float*)d_in[23];
  const float* g3  = (const float*)d_in[24]; const float* b3  = (const float*)d_in[25];
  const float* g4  = (const float*)d_in[26]; const float* b4  = (const float*)d_in[27];
  const float* hW  = (const float*)d_in[28]; const float* hb  = (const float*)d_in[29];
  float* out = (float*)d_out;

  // ---- workspace layout ----
  ushort_t* wqk  = (ushort_t*)d_ws;            // [1024][512] cWq^T | cWk^T
  ushort_t* wv   = wqk  + 524288;              // [512][512]
  ushort_t* wo   = wv   + 262144;
  ushort_t* wiqk = wo   + 262144;              // [1024][512] iWq^T | iWk^T
  ushort_t* wiv  = wiqk + 524288;
  ushort_t* wio  = wiv  + 262144;
  ushort_t* w1   = wio  + 262144;              // [2048][512]
  ushort_t* w2   = w1   + 1048576;             // [512][2048]
  float*  bqk  = (float*)(w2 + 1048576);       // [1024] cbq|cbk
  float*  biqk = bqk + 1024;                   // [1024] ibq|ibk
  float*    Xf = biqk + 1024;                  // f32 residual, NT*512
  ushort_t* Xb = (ushort_t*)(Xf + (size_t)NT * D_);   // bf16 activations
  ushort_t* QKb = Xb + (size_t)NT * D_;        // [NT][1024]   (also MLP H part 1)
  ushort_t* Vtb = QKb + (size_t)NT * 1024;     // [512][NT] or [NT][512] (H part 2)
  ushort_t* Ob  = Vtb + (size_t)NT * D_;       // [NT][512]    (H part 3)
  float*   comb = (float*)(Ob + (size_t)NT * D_);

  // ---- weight/bias prep ----
  transpose_bf16<<<dim3(16, 16), 256, 0, stream>>>(cWq, wqk, 512, 512);
  transpose_bf16<<<dim3(16, 16), 256, 0, stream>>>(cWk, wqk + 262144, 512, 512);
  transpose_bf16<<<dim3(16, 16), 256, 0, stream>>>(cWv, wv, 512, 512);
  transpose_bf16<<<dim3(16, 16), 256, 0, stream>>>(cWo, wo, 512, 512);
  transpose_bf16<<<dim3(16, 16), 256, 0, stream>>>(iWq, wiqk, 512, 512);
  transpose_bf16<<<dim3(16, 16), 256, 0, stream>>>(iWk, wiqk + 262144, 512, 512);
  transpose_bf16<<<dim3(16, 16), 256, 0, stream>>>(iWv, wiv, 512, 512);
  transpose_bf16<<<dim3(16, 16), 256, 0, stream>>>(iWo, wio, 512, 512);
  transpose_bf16<<<dim3(16, 64), 256, 0, stream>>>(mW1, w1, 512, 2048);
  transpose_bf16<<<dim3(64, 16), 256, 0, stream>>>(mW2, w2, 2048, 512);
  hipMemcpyAsync(bqk, cbq, 512 * 4, hipMemcpyDeviceToDevice, stream);
  hipMemcpyAsync(bqk + 512, cbk, 512 * 4, hipMemcpyDeviceToDevice, stream);
  hipMemcpyAsync(biqk, ibq, 512 * 4, hipMemcpyDeviceToDevice, stream);
  hipMemcpyAsync(biqk + 512, ibk, 512 * 4, hipMemcpyDeviceToDevice, stream);
  conv_bf16<<<dim3(NT * D_ / 8 / 256), 256, 0, stream>>>(ex, Xb, NT * D_ / 8);

  dim3 blk(256);

  // ---- block 1: attention over L ----
  gemm_mfma<false, false><<<dim3(NT / 128, 8), blk, 0, stream>>>(Xb, wqk, bqk, QKb, NT, 1024, 512);
  // V^T = (X @ cWv)^T : swap operands, row bias
  gemm_mfma<false, true><<<dim3(4, NT / 128), blk, 0, stream>>>(wv, Xb, cbv, Vtb, 512, NT, 512);
  attn_seq_mfma<<<dim3(768 * 8), blk, 0, stream>>>(QKb, Vtb, Ob);
  gemm_mfma<false, false><<<dim3(NT / 128, 4), blk, 0, stream>>>(Ob, wo, cbo, QKb, NT, 512, 512);
  add_ln<<<dim3(NT), blk, 0, stream>>>(ex, QKb, Xf, Xb, g1, b1);

  // ---- block 2: attention over C ----
  gemm_mfma<false, false><<<dim3(NT / 128, 8), blk, 0, stream>>>(Xb, wiqk, biqk, QKb, NT, 1024, 512);
  gemm_mfma<false, false><<<dim3(NT / 128, 4), blk, 0, stream>>>(Xb, wiv, ibv, Vtb, NT, 512, 512);
  attn_ctx<<<dim3(NT), dim3(64), 0, stream>>>(QKb, Vtb, Ob);
  gemm_mfma<false, false><<<dim3(NT / 128, 4), blk, 0, stream>>>(Ob, wio, ibo, QKb, NT, 512, 512);
  add_ln<<<dim3(NT), blk, 0, stream>>>(Xf, QKb, Xf, Xb, g3, b3);

  // ---- MLP: hidden H (bf16 NT*2048) overlays QKb|Vtb|Ob exactly ----
  gemm_mfma<true,  false><<<dim3(NT / 128, 16), blk, 0, stream>>>(Xb, w1, mb1, QKb, NT, 2048, 512);
  gemm_mfma<false, false><<<dim3(NT / 128, 4),  blk, 0, stream>>>(QKb, w2, mb2, Xb, NT, 512, 2048);
  add_ln<<<dim3(NT), blk, 0, stream>>>(Xf, Xb, Xf, (ushort_t*)nullptr, g4, b4);

  // ---- gated combine + head ----
  combine_last<<<dim3(BB * CC), dim3(512), 0, stream>>>(Xf, gates, comb);
  head_kernel<<<dim3(BB * CC), dim3(128), 0, stream>>>(comb, hW, hb, out);
}

// Round 4
// 940.383 us; speedup vs baseline: 7.4325x; 1.0884x over previous
//
#include <hip/hip_runtime.h>
#include <hip/hip_bf16.h>

#define NT   49152   // Ps*B*C*L tokens
#define D_   512
#define DF_  2048
#define PS   6
#define BB   16
#define CC   8
#define LL   64
#define PREDN 96

typedef unsigned short ushort_t;
using bf16x8 = __attribute__((ext_vector_type(8))) short;
using f32x4  = __attribute__((ext_vector_type(4))) float;

__device__ __forceinline__ float bf2f(unsigned short u) {
  return __uint_as_float((unsigned)u << 16);
}
__device__ __forceinline__ unsigned short f2bf(float f) {
  unsigned u = __float_as_uint(f);
  return (unsigned short)((u + 0x7fffu + ((u >> 16) & 1u)) >> 16);  // RNE
}
__device__ __forceinline__ void unp2(int x, float& a, float& b) {
  a = __uint_as_float((unsigned)x << 16);
  b = __uint_as_float((unsigned)x & 0xffff0000u);
}
__device__ __forceinline__ void gload16(const void* g, void* l) {
  __builtin_amdgcn_global_load_lds(
      (const __attribute__((address_space(1))) unsigned*)g,
      (__attribute__((address_space(3))) unsigned*)l, 16, 0, 0);
}

// ---------------------------------------------------------------------------
// bf16 MFMA GEMM: C[M,N] = A[M,K] @ Bt[N,K]^T + bias, bf16 out.
// BM=BN=128, BK=64, 256 threads (4 waves 2x2). Linear grid, col-fastest tile
// order + bijective XCD swizzle (T1/m204) for L2 locality of the A panel.
// ---------------------------------------------------------------------------
template <bool RELU, bool ROWBIAS>
__global__ __launch_bounds__(256) void gemm_mfma(
    const ushort_t* __restrict__ A,   // [M,K] bf16 row-major
    const ushort_t* __restrict__ Bt,  // [N,K] bf16 row-major
    const float* __restrict__ bias,
    ushort_t* __restrict__ C,         // [M,N] bf16
    int M, int N, int K) {
  __shared__ __align__(16) char smem[65536];
  short* Asm = (short*)smem;            // [2][128*64]
  short* Bsm = (short*)(smem + 32768);  // [2][128*64]
  const int tid = threadIdx.x;
  const int lane = tid & 63;
  const int w = tid >> 6;

  // --- tile index: XCD-swizzled, column-fastest ---
  const int nbn = N >> 7;
  const int nwg = gridDim.x;
  const int q = nwg >> 3, r = nwg & 7;
  const int xcd = blockIdx.x & 7, within = blockIdx.x >> 3;
  const int wg = (xcd < r ? xcd * (q + 1) : r * (q + 1) + (xcd - r) * q) + within;
  const int bn = (wg % nbn) * 128;
  const int bm = (wg / nbn) * 128;

  const int wr = (w >> 1) * 64;
  const int wc = (w & 1) * 64;
  f32x4 acc[4][4] = {};

  const int rowb = tid >> 3;
  const int kc = (tid & 7) << 3;

  auto stage = [&](int buf, int k0) {
#pragma unroll
    for (int it = 0; it < 4; ++it) {
      gload16(A + (size_t)(bm + it * 32 + rowb) * K + k0 + kc,
              Asm + buf * 8192 + it * 2048 + w * 512);
      gload16(Bt + (size_t)(bn + it * 32 + rowb) * K + k0 + kc,
              Bsm + buf * 8192 + it * 2048 + w * 512);
    }
  };
  auto compute = [&](int buf) {
    const short* ab = Asm + buf * 8192;
    const short* bb = Bsm + buf * 8192;
#pragma unroll
    for (int ks = 0; ks < 2; ++ks) {
      bf16x8 av[4], bv[4];
#pragma unroll
      for (int m = 0; m < 4; ++m)
        av[m] = *(const bf16x8*)(ab + (wr + m * 16 + (lane & 15)) * 64 + ks * 32 + (lane >> 4) * 8);
#pragma unroll
      for (int n = 0; n < 4; ++n)
        bv[n] = *(const bf16x8*)(bb + (wc + n * 16 + (lane & 15)) * 64 + ks * 32 + (lane >> 4) * 8);
#pragma unroll
      for (int m = 0; m < 4; ++m)
#pragma unroll
        for (int n = 0; n < 4; ++n)
          acc[m][n] = __builtin_amdgcn_mfma_f32_16x16x32_bf16(av[m], bv[n], acc[m][n], 0, 0, 0);
    }
  };

  const int nt = K >> 6;
  stage(0, 0);
  __syncthreads();
  for (int t = 0; t < nt; ++t) {
    if (t + 1 < nt) stage((t + 1) & 1, (t + 1) << 6);
    compute(t & 1);
    __syncthreads();
  }

  // Epilogue: acc -> LDS (f32, per-wave 64x64), then coalesced bf16x8 stores.
  float* Cs = (float*)smem;
  float* mc = Cs + (w << 12);
#pragma unroll
  for (int m = 0; m < 4; ++m)
#pragma unroll
    for (int n = 0; n < 4; ++n)
#pragma unroll
      for (int r2 = 0; r2 < 4; ++r2)
        mc[(m * 16 + (lane >> 4) * 4 + r2) * 64 + n * 16 + (lane & 15)] = acc[m][n][r2];
  __syncthreads();
#pragma unroll
  for (int it = 0; it < 8; ++it) {
    int chunk = it * 256 + tid;        // 0..2047
    int rr = chunk >> 4;                // 0..127
    int cc2 = (chunk & 15) << 3;        // 0..120
    const float* src = Cs + ((rr >> 6) * 2 + (cc2 >> 6)) * 4096 + (rr & 63) * 64 + (cc2 & 63);
    int gn = bn + cc2;
    union { unsigned short u[8]; int4 v; } pk;
#pragma unroll
    for (int j = 0; j < 8; ++j) {
      float v = src[j] + (ROWBIAS ? bias[bm + rr] : bias[gn + j]);
      if (RELU) v = fmaxf(v, 0.f);
      pk.u[j] = f2bf(v);
    }
    *(int4*)(C + (size_t)(bm + rr) * N + gn) = pk.v;
  }
}

// ---------------------------------------------------------------------------
__global__ __launch_bounds__(256) void transpose_bf16(
    const float* __restrict__ W, ushort_t* __restrict__ Wt, int K, int N) {
  __shared__ float tile[32][33];
  const int k0 = blockIdx.x * 32, n0 = blockIdx.y * 32;
  const int tx = threadIdx.x & 31, ty = threadIdx.x >> 5;
#pragma unroll
  for (int i = 0; i < 4; ++i)
    tile[ty + i * 8][tx] = W[(size_t)(k0 + ty + i * 8) * N + n0 + tx];
  __syncthreads();
#pragma unroll
  for (int i = 0; i < 4; ++i)
    Wt[(size_t)(n0 + ty + i * 8) * K + k0 + tx] = f2bf(tile[tx][ty + i * 8]);
}

__global__ __launch_bounds__(256) void conv_bf16(
    const float* __restrict__ in, ushort_t* __restrict__ out, int n8) {
  int i = blockIdx.x * 256 + threadIdx.x;
  if (i >= n8) return;
  const float4* p = (const float4*)in + (size_t)i * 2;
  float4 a = p[0], b = p[1];
  union { unsigned short u[8]; int4 v; } pk;
  pk.u[0] = f2bf(a.x); pk.u[1] = f2bf(a.y); pk.u[2] = f2bf(a.z); pk.u[3] = f2bf(a.w);
  pk.u[4] = f2bf(b.x); pk.u[5] = f2bf(b.y); pk.u[6] = f2bf(b.z); pk.u[7] = f2bf(b.w);
  ((int4*)out)[i] = pk.v;
}

// ---------------------------------------------------------------------------
// MFMA attention over sequence axis (S=64, dh=64). One block per (group,head).
// QK: [NT][1024] fused Q|K. Vt: [512][NT] transposed V. O: [NT][512].
// ---------------------------------------------------------------------------
__global__ __launch_bounds__(256) void attn_seq_mfma(
    const ushort_t* __restrict__ QK, const ushort_t* __restrict__ Vt,
    ushort_t* __restrict__ O) {
  __shared__ __align__(16) char smem[27648];
  short* qs = (short*)smem;            // [64][72] bf16; later P; later O
  short* ks = (short*)(smem + 9216);   // [64][72] bf16
  short* vt = (short*)(smem + 18432);  // [64][72] bf16 (V^T tile: [d][t])
  float* S  = (float*)smem;            // [64][66] f32 (overlays qs+ks)
  const int h = blockIdx.x & 7;
  const int g = blockIdx.x >> 3;
  const int tid = threadIdx.x;
  const int lane = tid & 63;
  const int w = tid >> 6;
  const int wr = (w >> 1) * 32, wc = (w & 1) * 32;

  {
    const size_t qkbase = (size_t)g * 64 * 1024 + h * 64;
    const size_t vbase  = (size_t)(h * 64) * NT + (size_t)g * 64;
#pragma unroll
    for (int it = 0; it < 2; ++it) {
      int t = it * 256 + tid;            // 0..511
      int r = t >> 3, c = (t & 7) * 8;
      int4 qv = *(const int4*)(QK + qkbase + (size_t)r * 1024 + c);
      int4 kv = *(const int4*)(QK + qkbase + (size_t)r * 1024 + 512 + c);
      int4 vv = *(const int4*)(Vt + vbase + (size_t)r * NT + c);
      *(int4*)(qs + r * 72 + c) = qv;
      *(int4*)(ks + r * 72 + c) = kv;
      *(int4*)(vt + r * 72 + c) = vv;
    }
  }
  __syncthreads();

  // S = Q K^T (raw; scale folded into softmax)
  f32x4 acc[2][2] = {};
#pragma unroll
  for (int k2 = 0; k2 < 2; ++k2) {
    bf16x8 aq[2], bk[2];
#pragma unroll
    for (int m = 0; m < 2; ++m)
      aq[m] = *(const bf16x8*)(qs + (wr + m * 16 + (lane & 15)) * 72 + k2 * 32 + (lane >> 4) * 8);
#pragma unroll
    for (int n = 0; n < 2; ++n)
      bk[n] = *(const bf16x8*)(ks + (wc + n * 16 + (lane & 15)) * 72 + k2 * 32 + (lane >> 4) * 8);
#pragma unroll
    for (int m = 0; m < 2; ++m)
#pragma unroll
      for (int n = 0; n < 2; ++n)
        acc[m][n] = __builtin_amdgcn_mfma_f32_16x16x32_bf16(aq[m], bk[n], acc[m][n], 0, 0, 0);
  }
  __syncthreads();
#pragma unroll
  for (int m = 0; m < 2; ++m)
#pragma unroll
    for (int n = 0; n < 2; ++n)
#pragma unroll
      for (int r = 0; r < 4; ++r)
        S[(wr + m * 16 + (lane >> 4) * 4 + r) * 66 + wc + n * 16 + (lane & 15)] = acc[m][n][r];
  __syncthreads();

  // wave-parallel softmax: 4 lanes per row, 16 cols each
  {
    int row = tid >> 2, qq = tid & 3;
    float v[16];
    float mx = -1e30f;
#pragma unroll
    for (int j = 0; j < 16; ++j) { v[j] = S[row * 66 + qq * 16 + j]; mx = fmaxf(mx, v[j]); }
    mx = fmaxf(mx, __shfl_xor(mx, 1));
    mx = fmaxf(mx, __shfl_xor(mx, 2));
    float sum = 0.f;
#pragma unroll
    for (int j = 0; j < 16; ++j) { v[j] = __expf((v[j] - mx) * 0.125f); sum += v[j]; }
    sum += __shfl_xor(sum, 1);
    sum += __shfl_xor(sum, 2);
    float inv = 1.f / sum;
    __syncthreads();   // all S reads complete before P overwrites the region
    union { unsigned short u[16]; int4 i4[2]; } pk;
#pragma unroll
    for (int j = 0; j < 16; ++j) pk.u[j] = f2bf(v[j] * inv);
    *(int4*)(qs + row * 72 + qq * 16) = pk.i4[0];
    *(int4*)(qs + row * 72 + qq * 16 + 8) = pk.i4[1];
  }
  __syncthreads();

  // O = P V  (A = P rows, B = vt rows = V columns)
  f32x4 acc2[2][2] = {};
#pragma unroll
  for (int k2 = 0; k2 < 2; ++k2) {
    bf16x8 ap[2], bv[2];
#pragma unroll
    for (int m = 0; m < 2; ++m)
      ap[m] = *(const bf16x8*)(qs + (wr + m * 16 + (lane & 15)) * 72 + k2 * 32 + (lane >> 4) * 8);
#pragma unroll
    for (int n = 0; n < 2; ++n)
      bv[n] = *(const bf16x8*)(vt + (wc + n * 16 + (lane & 15)) * 72 + k2 * 32 + (lane >> 4) * 8);
#pragma unroll
    for (int m = 0; m < 2; ++m)
#pragma unroll
      for (int n = 0; n < 2; ++n)
        acc2[m][n] = __builtin_amdgcn_mfma_f32_16x16x32_bf16(ap[m], bv[n], acc2[m][n], 0, 0, 0);
  }
  __syncthreads();
  short* Os = qs;   // reuse as bf16 [64][72]
#pragma unroll
  for (int m = 0; m < 2; ++m)
#pragma unroll
    for (int n = 0; n < 2; ++n)
#pragma unroll
      for (int r = 0; r < 4; ++r)
        Os[(wr + m * 16 + (lane >> 4) * 4 + r) * 72 + wc + n * 16 + (lane & 15)] = f2bf(acc2[m][n][r]);
  __syncthreads();
#pragma unroll
  for (int it = 0; it < 2; ++it) {
    int t = it * 256 + tid;
    int r = t >> 3, c = (t & 7) * 8;
    *(int4*)(O + (size_t)(g * 64 + r) * 512 + h * 64 + c) = *(const int4*)(Os + r * 72 + c);
  }
}

// ---------------------------------------------------------------------------
// Attention over context axis (S=8, dh=64). QKV fused: [NT][1536] = Q|K|V.
// ---------------------------------------------------------------------------
__global__ __launch_bounds__(64) void attn_ctx(
    const ushort_t* __restrict__ QKV, ushort_t* __restrict__ O) {
  __shared__ float qs[8][72], ks[8][72], vs[8][72], ps[8][9];
  const int h = blockIdx.x & 7;
  const int l = (blockIdx.x >> 3) & 63;
  const int pb = blockIdx.x >> 9;
  const size_t row0 = (size_t)pb * 512 + l;
  const int tid = threadIdx.x;
  {
    int c = tid >> 3, dc = (tid & 7) * 8;
    size_t r = row0 + (size_t)c * 64;
    int4 qv = *(const int4*)(QKV + r * 1536 + h * 64 + dc);
    int4 kv = *(const int4*)(QKV + r * 1536 + 512 + h * 64 + dc);
    int4 vv = *(const int4*)(QKV + r * 1536 + 1024 + h * 64 + dc);
    unp2(qv.x, qs[c][dc + 0], qs[c][dc + 1]); unp2(qv.y, qs[c][dc + 2], qs[c][dc + 3]);
    unp2(qv.z, qs[c][dc + 4], qs[c][dc + 5]); unp2(qv.w, qs[c][dc + 6], qs[c][dc + 7]);
    unp2(kv.x, ks[c][dc + 0], ks[c][dc + 1]); unp2(kv.y, ks[c][dc + 2], ks[c][dc + 3]);
    unp2(kv.z, ks[c][dc + 4], ks[c][dc + 5]); unp2(kv.w, ks[c][dc + 6], ks[c][dc + 7]);
    unp2(vv.x, vs[c][dc + 0], vs[c][dc + 1]); unp2(vv.y, vs[c][dc + 2], vs[c][dc + 3]);
    unp2(vv.z, vs[c][dc + 4], vs[c][dc + 5]); unp2(vv.w, vs[c][dc + 6], vs[c][dc + 7]);
  }
  __syncthreads();
  {
    int i = tid >> 3, t = tid & 7;
    float s = 0.f;
#pragma unroll
    for (int d = 0; d < 64; ++d) s += qs[i][d] * ks[t][d];
    ps[i][t] = s * 0.125f;
  }
  __syncthreads();
  if (tid < 8) {
    float mx = -1e30f;
#pragma unroll
    for (int t = 0; t < 8; ++t) mx = fmaxf(mx, ps[tid][t]);
    float sum = 0.f;
#pragma unroll
    for (int t = 0; t < 8; ++t) { float e = __expf(ps[tid][t] - mx); ps[tid][t] = e; sum += e; }
    float inv = 1.f / sum;
#pragma unroll
    for (int t = 0; t < 8; ++t) ps[tid][t] *= inv;
  }
  __syncthreads();
#pragma unroll
  for (int c = 0; c < 8; ++c) {
    float s = 0.f;
#pragma unroll
    for (int t = 0; t < 8; ++t) s += ps[c][t] * vs[t][tid];
    O[(row0 + (size_t)c * 64) * D_ + h * 64 + tid] = f2bf(s);
  }
}

// ---------------------------------------------------------------------------
// Xout(bf16) = LN(Xin + T) * g + b. Residual stream is bf16 (except first: f32 ex).
// Xin/Xout may alias (per-thread read-before-write). ushort2 loads (4B/lane).
// ---------------------------------------------------------------------------
template <bool INF32>
__global__ __launch_bounds__(256) void add_ln(
    const void* Xin, const ushort_t* T, ushort_t* Xout,
    const float* __restrict__ g, const float* __restrict__ b) {
  const size_t off = (size_t)blockIdx.x * D_;
  const int tid = threadIdx.x;
  float x0, x1;
  if (INF32) {
    float2 xv = ((const float2*)((const float*)Xin + off))[tid];
    x0 = xv.x; x1 = xv.y;
  } else {
    ushort2 xv = ((const ushort2*)((const ushort_t*)Xin + off))[tid];
    x0 = bf2f(xv.x); x1 = bf2f(xv.y);
  }
  ushort2 tv = ((const ushort2*)(T + off))[tid];
  x0 += bf2f(tv.x);
  x1 += bf2f(tv.y);
  float s = x0 + x1, q = x0 * x0 + x1 * x1;
#pragma unroll
  for (int o = 32; o > 0; o >>= 1) { s += __shfl_down(s, o); q += __shfl_down(q, o); }
  __shared__ float ssum[4], sqsum[4];
  if ((tid & 63) == 0) { ssum[tid >> 6] = s; sqsum[tid >> 6] = q; }
  __syncthreads();
  float S = ssum[0] + ssum[1] + ssum[2] + ssum[3];
  float Qs = sqsum[0] + sqsum[1] + sqsum[2] + sqsum[3];
  float m = S * (1.f / D_);
  float var = Qs * (1.f / D_) - m * m;
  float inv = rsqrtf(var + 1e-5f);
  float y0 = (x0 - m) * inv * g[tid * 2] + b[tid * 2];
  float y1 = (x1 - m) * inv * g[tid * 2 + 1] + b[tid * 2 + 1];
  ushort2 ov; ov.x = f2bf(y0); ov.y = f2bf(y1);
  ((ushort2*)(Xout + off))[tid] = ov;
}

__global__ __launch_bounds__(512) void combine_last(
    const ushort_t* __restrict__ X, const float* __restrict__ gates,
    float* __restrict__ comb) {
  const int b = blockIdx.x >> 3, c = blockIdx.x & 7;
  const int d = threadIdx.x;
  float s = 0.f;
#pragma unroll
  for (int p = 0; p < PS; ++p) {
    size_t row = ((size_t)(p * BB + b) * CC + c) * LL + (LL - 1);
    s += gates[b * PS + p] * bf2f(X[row * D_ + d]);
  }
  comb[(size_t)blockIdx.x * D_ + d] = s;
}

__global__ __launch_bounds__(128) void head_kernel(
    const float* __restrict__ comb, const float* __restrict__ hW,
    const float* __restrict__ hb, float* __restrict__ out) {
  __shared__ float xr[D_];
  const int bc = blockIdx.x;
  for (int i = threadIdx.x; i < D_; i += 128) xr[i] = comb[(size_t)bc * D_ + i];
  __syncthreads();
  const int n = threadIdx.x;
  if (n < PREDN) {
    float s = hb[n];
    for (int d = 0; d < D_; ++d) s += xr[d] * hW[d * PREDN + n];
    const int b = bc >> 3, c = bc & 7;
    out[((size_t)b * PREDN + n) * CC + c] = s;
  }
}

// ---------------------------------------------------------------------------
extern "C" void kernel_launch(void* const* d_in, const int* in_sizes, int n_in,
                              void* d_out, int out_size, void* d_ws, size_t ws_size,
                              hipStream_t stream) {
  const float* ex    = (const float*)d_in[0];
  const float* gates = (const float*)d_in[1];
  const float* cWq = (const float*)d_in[2];  const float* cbq = (const float*)d_in[3];
  const float* cWk = (const float*)d_in[4];  const float* cbk = (const float*)d_in[5];
  const float* cWv = (const float*)d_in[6];  const float* cbv = (const float*)d_in[7];
  const float* cWo = (const float*)d_in[8];  const float* cbo = (const float*)d_in[9];
  const float* iWq = (const float*)d_in[10]; const float* ibq = (const float*)d_in[11];
  const float* iWk = (const float*)d_in[12]; const float* ibk = (const float*)d_in[13];
  const float* iWv = (const float*)d_in[14]; const float* ibv = (const float*)d_in[15];
  const float* iWo = (const float*)d_in[16]; const float* ibo = (const float*)d_in[17];
  const float* mW1 = (const float*)d_in[18]; const float* mb1 = (const float*)d_in[19];
  const float* mW2 = (const float*)d_in[20]; const float* mb2 = (const float*)d_in[21];
  const float* g1  = (const float*)d_in[22]; const float* b1  = (const float*)d_in[23];
  const float* g3  = (const float*)d_in[24]; const float* b3  = (const float*)d_in[25];
  const float* g4  = (const float*)d_in[26]; const float* b4  = (const float*)d_in[27];
  const float* hW  = (const float*)d_in[28]; const float* hb  = (const float*)d_in[29];
  float* out = (float*)d_out;

  // ---- workspace layout ----
  ushort_t* wqk  = (ushort_t*)d_ws;            // [1024][512] cWq^T | cWk^T
  ushort_t* wv   = wqk  + 524288;              // [512][512]
  ushort_t* wo   = wv   + 262144;
  ushort_t* wiqkv= wo   + 262144;              // [1536][512] iWq^T|iWk^T|iWv^T
  ushort_t* wio  = wiqkv+ 786432;
  ushort_t* w1   = wio  + 262144;              // [2048][512]
  ushort_t* w2   = w1   + 1048576;             // [512][2048]
  float*  bqk  = (float*)(w2 + 1048576);       // [1024] cbq|cbk
  float*  biqkv= bqk + 1024;                   // [1536] ibq|ibk|ibv
  ushort_t* Xb = (ushort_t*)(biqkv + 1536);    // bf16 residual stream, NT*512
  ushort_t* QKb = Xb + (size_t)NT * D_;        // [NT][1024] (blk1) / QKV [NT][1536] (blk2) / MLP H
  ushort_t* Vtb = QKb + (size_t)NT * 1024;     // [512][NT] (blk1) — part of QKV/H region
  ushort_t* Ob  = Vtb + (size_t)NT * D_;       // [NT][512] attn out / H part 3
  ushort_t* Tb  = Ob + (size_t)NT * D_;        // [NT][512] MLP out (disjoint from H)
  float*   comb = (float*)(Tb + (size_t)NT * D_);

  // ---- weight/bias prep ----
  transpose_bf16<<<dim3(16, 16), 256, 0, stream>>>(cWq, wqk, 512, 512);
  transpose_bf16<<<dim3(16, 16), 256, 0, stream>>>(cWk, wqk + 262144, 512, 512);
  transpose_bf16<<<dim3(16, 16), 256, 0, stream>>>(cWv, wv, 512, 512);
  transpose_bf16<<<dim3(16, 16), 256, 0, stream>>>(cWo, wo, 512, 512);
  transpose_bf16<<<dim3(16, 16), 256, 0, stream>>>(iWq, wiqkv, 512, 512);
  transpose_bf16<<<dim3(16, 16), 256, 0, stream>>>(iWk, wiqkv + 262144, 512, 512);
  transpose_bf16<<<dim3(16, 16), 256, 0, stream>>>(iWv, wiqkv + 524288, 512, 512);
  transpose_bf16<<<dim3(16, 16), 256, 0, stream>>>(iWo, wio, 512, 512);
  transpose_bf16<<<dim3(16, 64), 256, 0, stream>>>(mW1, w1, 512, 2048);
  transpose_bf16<<<dim3(64, 16), 256, 0, stream>>>(mW2, w2, 2048, 512);
  hipMemcpyAsync(bqk, cbq, 512 * 4, hipMemcpyDeviceToDevice, stream);
  hipMemcpyAsync(bqk + 512, cbk, 512 * 4, hipMemcpyDeviceToDevice, stream);
  hipMemcpyAsync(biqkv, ibq, 512 * 4, hipMemcpyDeviceToDevice, stream);
  hipMemcpyAsync(biqkv + 512, ibk, 512 * 4, hipMemcpyDeviceToDevice, stream);
  hipMemcpyAsync(biqkv + 1024, ibv, 512 * 4, hipMemcpyDeviceToDevice, stream);
  conv_bf16<<<dim3(NT * D_ / 8 / 256), 256, 0, stream>>>(ex, Xb, NT * D_ / 8);

  dim3 blk(256);
  const int RT = NT / 128;  // 384 row tiles

  // ---- block 1: attention over L ----
  gemm_mfma<false, false><<<dim3(RT * 8), blk, 0, stream>>>(Xb, wqk, bqk, QKb, NT, 1024, 512);
  gemm_mfma<false, true ><<<dim3(4 * RT), blk, 0, stream>>>(wv, Xb, cbv, Vtb, 512, NT, 512);
  attn_seq_mfma<<<dim3(768 * 8), blk, 0, stream>>>(QKb, Vtb, Ob);
  gemm_mfma<false, false><<<dim3(RT * 4), blk, 0, stream>>>(Ob, wo, cbo, Tb, NT, 512, 512);
  add_ln<true><<<dim3(NT), blk, 0, stream>>>(ex, Tb, Xb, g1, b1);

  // ---- block 2: attention over C (fused QKV, N=1536) ----
  gemm_mfma<false, false><<<dim3(RT * 12), blk, 0, stream>>>(Xb, wiqkv, biqkv, QKb, NT, 1536, 512);
  attn_ctx<<<dim3(NT), dim3(64), 0, stream>>>(QKb, Ob);
  gemm_mfma<false, false><<<dim3(RT * 4), blk, 0, stream>>>(Ob, wio, ibo, Tb, NT, 512, 512);
  add_ln<false><<<dim3(NT), blk, 0, stream>>>(Xb, Tb, Xb, g3, b3);

  // ---- MLP: hidden H (bf16 NT*2048) overlays QKb..Ob; out -> Tb ----
  gemm_mfma<true,  false><<<dim3(RT * 16), blk, 0, stream>>>(Xb, w1, mb1, QKb, NT, 2048, 512);
  gemm_mfma<false, false><<<dim3(RT * 4),  blk, 0, stream>>>(QKb, w2, mb2, Tb, NT, 512, 2048);
  add_ln<false><<<dim3(NT), blk, 0, stream>>>(Xb, Tb, Xb, g4, b4);

  // ---- gated combine + head ----
  combine_last<<<dim3(BB * CC), dim3(512), 0, stream>>>(Xb, gates, comb);
  head_kernel<<<dim3(BB * CC), dim3(128), 0, stream>>>(comb, hW, hb, out);
}

// Round 5
// 818.703 us; speedup vs baseline: 8.5371x; 1.1486x over previous
//
#include <hip/hip_runtime.h>
#include <hip/hip_bf16.h>

#define NT   49152   // Ps*B*C*L tokens
#define D_   512
#define DF_  2048
#define PS   6
#define BB   16
#define CC   8
#define LL   64
#define PREDN 96

typedef unsigned short ushort_t;
using bf16x8 = __attribute__((ext_vector_type(8))) short;
using f32x4  = __attribute__((ext_vector_type(4))) float;

__device__ __forceinline__ float bf2f(unsigned short u) {
  return __uint_as_float((unsigned)u << 16);
}
__device__ __forceinline__ unsigned short f2bf(float f) {
  unsigned u = __float_as_uint(f);
  return (unsigned short)((u + 0x7fffu + ((u >> 16) & 1u)) >> 16);  // RNE
}
__device__ __forceinline__ void unp2(int x, float& a, float& b) {
  a = __uint_as_float((unsigned)x << 16);
  b = __uint_as_float((unsigned)x & 0xffff0000u);
}
__device__ __forceinline__ void gload16(const void* g, void* l) {
  __builtin_amdgcn_global_load_lds(
      (const __attribute__((address_space(1))) unsigned*)g,
      (__attribute__((address_space(3))) unsigned*)l, 16, 0, 0);
}

// ---------------------------------------------------------------------------
// bf16 MFMA GEMM, counted-vmcnt pipelined (T3/T4/T5/T2).
// C[M,N] = A[M,K] @ Bt[N,K]^T + bias, bf16 out.
// BM=256, BN=128, BK=32, 512 threads = 8 waves (4M x 2N), per-wave 64x64.
// LDS: 3 buffers x (A 16KB + B 8KB) = 72 KB, prefetch distance 2 K-tiles,
// s_waitcnt vmcnt(3) per iteration (never 0 in main loop), raw s_barrier only.
// LDS chunk swizzle: physical 16B-chunk = logical ^ ((row>>1)&3), applied to
// BOTH the pre-swizzled global source of global_load_lds and the ds_read addr.
// M%256==0, N%128==0, K%32==0, K>=64, grid %8==0 (all call sites satisfy).
// ---------------------------------------------------------------------------
template <bool RELU, bool ROWBIAS>
__global__ __launch_bounds__(512, 2) void gemm_mfma(
    const ushort_t* __restrict__ A,   // [M,K] bf16 row-major
    const ushort_t* __restrict__ Bt,  // [N,K] bf16 row-major
    const float* __restrict__ bias,
    ushort_t* __restrict__ C,         // [M,N] bf16
    int M, int N, int K) {
  __shared__ __align__(16) char smem[73728];
  short* lds = (short*)smem;
  const int tid = threadIdx.x;
  const int lane = tid & 63;
  const int w = tid >> 6;       // 0..7
  const int wm = w >> 1;        // 0..3  (M-quadrant, 64 rows)
  const int wn = w & 1;         // 0..1  (N-half, 64 cols)
  const int l15 = lane & 15, l4 = lane >> 4;

  // --- tile index: XCD-swizzled (bijective), column-fastest ---
  const int nbn = N >> 7;
  const int nwg = gridDim.x;
  const int qq = nwg >> 3, rr = nwg & 7;
  const int xcd = blockIdx.x & 7, within = blockIdx.x >> 3;
  const int wg = (xcd < rr ? xcd * (qq + 1) : rr * (qq + 1) + (xcd - rr) * qq) + within;
  const int bn = (wg % nbn) << 7;
  const int bm = (wg / nbn) << 8;

  const int NKT = K >> 5;

  // --- staging source coords (per-lane, swizzle pre-applied to global addr) ---
  // A: 1024 chunks of 16B (256 rows x 4 chunks); issues i=0,1 per wave.
  // B: 512 chunks (128 rows x 4); one issue per wave.
  const int ciA0 = w * 64 + lane;           // i=0: chunks 0..511   (rows 0..127)
  const int ciA1 = 512 + w * 64 + lane;     // i=1: chunks 512..1023(rows 128..255)
  const int ciB  = w * 64 + lane;
  const int rA0 = ciA0 >> 2, rA1 = ciA1 >> 2, rB = ciB >> 2;
  const int jA0 = (ciA0 & 3) ^ ((rA0 >> 1) & 3);
  const int jA1 = (ciA1 & 3) ^ ((rA1 >> 1) & 3);
  const int jB  = (ciB  & 3) ^ ((rB  >> 1) & 3);
  const ushort_t* gA0 = A + (size_t)(bm + rA0) * K + (jA0 << 3);
  const ushort_t* gA1 = A + (size_t)(bm + rA1) * K + (jA1 << 3);
  const ushort_t* gB  = Bt + (size_t)(bn + rB) * K + (jB << 3);

  auto stage = [&](int st, int sb) {  // stage K-tile st into buffer sb
    const int k0 = st << 5;
    gload16(gA0 + k0, smem + sb * 24576 + w * 1024);
    gload16(gA1 + k0, smem + sb * 24576 + 8192 + w * 1024);
    gload16(gB  + k0, smem + sb * 24576 + 16384 + w * 1024);
  };

  // --- ds_read fragment offsets (shorts), swizzled chunk within 64B row ---
  int aconst[4], bconst[4];
#pragma unroll
  for (int m = 0; m < 4; ++m) {
    int row = wm * 64 + m * 16 + l15;
    aconst[m] = row * 32 + ((l4 ^ ((row >> 1) & 3)) << 3);
  }
#pragma unroll
  for (int n = 0; n < 4; ++n) {
    int row = wn * 64 + n * 16 + l15;
    bconst[n] = 8192 + row * 32 + ((l4 ^ ((row >> 1) & 3)) << 3);
  }

  f32x4 acc[4][4] = {};

  // --- prologue: stage tiles 0,1 ---
  stage(0, 0);
  stage(1, 1);

  int rb = 0, sb = 2;
  for (int kt = 0; kt < NKT; ++kt) {
    asm volatile("s_waitcnt vmcnt(3)" ::: "memory");
    __builtin_amdgcn_s_barrier();
    const short* buf = lds + rb * 12288;
    bf16x8 av[4], bv[4];
#pragma unroll
    for (int m = 0; m < 4; ++m) av[m] = *(const bf16x8*)(buf + aconst[m]);
#pragma unroll
    for (int n = 0; n < 4; ++n) bv[n] = *(const bf16x8*)(buf + bconst[n]);
    const int st = (kt + 2 < NKT) ? kt + 2 : NKT - 1;
    stage(st, sb);
    __builtin_amdgcn_s_barrier();
    __builtin_amdgcn_s_setprio(1);
#pragma unroll
    for (int m = 0; m < 4; ++m)
#pragma unroll
      for (int n = 0; n < 4; ++n)
        acc[m][n] = __builtin_amdgcn_mfma_f32_16x16x32_bf16(av[m], bv[n], acc[m][n], 0, 0, 0);
    __builtin_amdgcn_s_setprio(0);
    rb = (rb == 2) ? 0 : rb + 1;
    sb = (sb == 2) ? 0 : sb + 1;
  }

  // --- drain outstanding (clamped junk) stages before LDS reuse ---
  asm volatile("s_waitcnt vmcnt(0)" ::: "memory");
  __syncthreads();

  // --- epilogue: bias/ReLU in-register, bf16 stage to LDS, coalesced stores ---
  float bc[4];
  float br[4][4];
  if (ROWBIAS) {
#pragma unroll
    for (int m = 0; m < 4; ++m)
#pragma unroll
      for (int r2 = 0; r2 < 4; ++r2)
        br[m][r2] = bias[bm + wm * 64 + m * 16 + l4 * 4 + r2];
  } else {
#pragma unroll
    for (int n = 0; n < 4; ++n) bc[n] = bias[bn + wn * 64 + n * 16 + l15];
  }
  short* Cs = lds;  // [256][136] bf16 (pad 8 shorts -> 16B-aligned rows)
#pragma unroll
  for (int m = 0; m < 4; ++m)
#pragma unroll
    for (int n = 0; n < 4; ++n)
#pragma unroll
      for (int r2 = 0; r2 < 4; ++r2) {
        float v = acc[m][n][r2] + (ROWBIAS ? br[m][r2] : bc[n]);
        if (RELU) v = fmaxf(v, 0.f);
        Cs[(wm * 64 + m * 16 + l4 * 4 + r2) * 136 + wn * 64 + n * 16 + l15] =
            (short)f2bf(v);
      }
  __syncthreads();
#pragma unroll
  for (int it = 0; it < 8; ++it) {
    int chunk = it * 512 + tid;     // 0..4095
    int r = chunk >> 4;              // 0..255
    int c = (chunk & 15) << 3;       // 0..120
    int4 v = *(const int4*)(Cs + r * 136 + c);
    *(int4*)(C + (size_t)(bm + r) * N + bn + c) = v;
  }
}

// ---------------------------------------------------------------------------
__global__ __launch_bounds__(256) void transpose_bf16(
    const float* __restrict__ W, ushort_t* __restrict__ Wt, int K, int N) {
  __shared__ float tile[32][33];
  const int k0 = blockIdx.x * 32, n0 = blockIdx.y * 32;
  const int tx = threadIdx.x & 31, ty = threadIdx.x >> 5;
#pragma unroll
  for (int i = 0; i < 4; ++i)
    tile[ty + i * 8][tx] = W[(size_t)(k0 + ty + i * 8) * N + n0 + tx];
  __syncthreads();
#pragma unroll
  for (int i = 0; i < 4; ++i)
    Wt[(size_t)(n0 + ty + i * 8) * K + k0 + tx] = f2bf(tile[tx][ty + i * 8]);
}

__global__ __launch_bounds__(256) void conv_bf16(
    const float* __restrict__ in, ushort_t* __restrict__ out, int n8) {
  int i = blockIdx.x * 256 + threadIdx.x;
  if (i >= n8) return;
  const float4* p = (const float4*)in + (size_t)i * 2;
  float4 a = p[0], b = p[1];
  union { unsigned short u[8]; int4 v; } pk;
  pk.u[0] = f2bf(a.x); pk.u[1] = f2bf(a.y); pk.u[2] = f2bf(a.z); pk.u[3] = f2bf(a.w);
  pk.u[4] = f2bf(b.x); pk.u[5] = f2bf(b.y); pk.u[6] = f2bf(b.z); pk.u[7] = f2bf(b.w);
  ((int4*)out)[i] = pk.v;
}

// ---------------------------------------------------------------------------
// MFMA attention over sequence axis (S=64, dh=64). One block per (group,head).
// QK: [NT][1024] fused Q|K. Vt: [512][NT] transposed V. O: [NT][512].
// ---------------------------------------------------------------------------
__global__ __launch_bounds__(256) void attn_seq_mfma(
    const ushort_t* __restrict__ QK, const ushort_t* __restrict__ Vt,
    ushort_t* __restrict__ O) {
  __shared__ __align__(16) char smem[27648];
  short* qs = (short*)smem;            // [64][72] bf16; later P; later O
  short* ks = (short*)(smem + 9216);   // [64][72] bf16
  short* vt = (short*)(smem + 18432);  // [64][72] bf16 (V^T tile: [d][t])
  float* S  = (float*)smem;            // [64][66] f32 (overlays qs+ks)
  const int h = blockIdx.x & 7;
  const int g = blockIdx.x >> 3;
  const int tid = threadIdx.x;
  const int lane = tid & 63;
  const int w = tid >> 6;
  const int wr = (w >> 1) * 32, wc = (w & 1) * 32;

  {
    const size_t qkbase = (size_t)g * 64 * 1024 + h * 64;
    const size_t vbase  = (size_t)(h * 64) * NT + (size_t)g * 64;
#pragma unroll
    for (int it = 0; it < 2; ++it) {
      int t = it * 256 + tid;            // 0..511
      int r = t >> 3, c = (t & 7) * 8;
      int4 qv = *(const int4*)(QK + qkbase + (size_t)r * 1024 + c);
      int4 kv = *(const int4*)(QK + qkbase + (size_t)r * 1024 + 512 + c);
      int4 vv = *(const int4*)(Vt + vbase + (size_t)r * NT + c);
      *(int4*)(qs + r * 72 + c) = qv;
      *(int4*)(ks + r * 72 + c) = kv;
      *(int4*)(vt + r * 72 + c) = vv;
    }
  }
  __syncthreads();

  // S = Q K^T (raw; scale folded into softmax)
  f32x4 acc[2][2] = {};
#pragma unroll
  for (int k2 = 0; k2 < 2; ++k2) {
    bf16x8 aq[2], bk[2];
#pragma unroll
    for (int m = 0; m < 2; ++m)
      aq[m] = *(const bf16x8*)(qs + (wr + m * 16 + (lane & 15)) * 72 + k2 * 32 + (lane >> 4) * 8);
#pragma unroll
    for (int n = 0; n < 2; ++n)
      bk[n] = *(const bf16x8*)(ks + (wc + n * 16 + (lane & 15)) * 72 + k2 * 32 + (lane >> 4) * 8);
#pragma unroll
    for (int m = 0; m < 2; ++m)
#pragma unroll
      for (int n = 0; n < 2; ++n)
        acc[m][n] = __builtin_amdgcn_mfma_f32_16x16x32_bf16(aq[m], bk[n], acc[m][n], 0, 0, 0);
  }
  __syncthreads();
#pragma unroll
  for (int m = 0; m < 2; ++m)
#pragma unroll
    for (int n = 0; n < 2; ++n)
#pragma unroll
      for (int r = 0; r < 4; ++r)
        S[(wr + m * 16 + (lane >> 4) * 4 + r) * 66 + wc + n * 16 + (lane & 15)] = acc[m][n][r];
  __syncthreads();

  // wave-parallel softmax: 4 lanes per row, 16 cols each
  {
    int row = tid >> 2, qq = tid & 3;
    float v[16];
    float mx = -1e30f;
#pragma unroll
    for (int j = 0; j < 16; ++j) { v[j] = S[row * 66 + qq * 16 + j]; mx = fmaxf(mx, v[j]); }
    mx = fmaxf(mx, __shfl_xor(mx, 1));
    mx = fmaxf(mx, __shfl_xor(mx, 2));
    float sum = 0.f;
#pragma unroll
    for (int j = 0; j < 16; ++j) { v[j] = __expf((v[j] - mx) * 0.125f); sum += v[j]; }
    sum += __shfl_xor(sum, 1);
    sum += __shfl_xor(sum, 2);
    float inv = 1.f / sum;
    __syncthreads();   // all S reads complete before P overwrites the region
    union { unsigned short u[16]; int4 i4[2]; } pk;
#pragma unroll
    for (int j = 0; j < 16; ++j) pk.u[j] = f2bf(v[j] * inv);
    *(int4*)(qs + row * 72 + qq * 16) = pk.i4[0];
    *(int4*)(qs + row * 72 + qq * 16 + 8) = pk.i4[1];
  }
  __syncthreads();

  // O = P V  (A = P rows, B = vt rows = V columns)
  f32x4 acc2[2][2] = {};
#pragma unroll
  for (int k2 = 0; k2 < 2; ++k2) {
    bf16x8 ap[2], bv[2];
#pragma unroll
    for (int m = 0; m < 2; ++m)
      ap[m] = *(const bf16x8*)(qs + (wr + m * 16 + (lane & 15)) * 72 + k2 * 32 + (lane >> 4) * 8);
#pragma unroll
    for (int n = 0; n < 2; ++n)
      bv[n] = *(const bf16x8*)(vt + (wc + n * 16 + (lane & 15)) * 72 + k2 * 32 + (lane >> 4) * 8);
#pragma unroll
    for (int m = 0; m < 2; ++m)
#pragma unroll
      for (int n = 0; n < 2; ++n)
        acc2[m][n] = __builtin_amdgcn_mfma_f32_16x16x32_bf16(ap[m], bv[n], acc2[m][n], 0, 0, 0);
  }
  __syncthreads();
  short* Os = qs;   // reuse as bf16 [64][72]
#pragma unroll
  for (int m = 0; m < 2; ++m)
#pragma unroll
    for (int n = 0; n < 2; ++n)
#pragma unroll
      for (int r = 0; r < 4; ++r)
        Os[(wr + m * 16 + (lane >> 4) * 4 + r) * 72 + wc + n * 16 + (lane & 15)] = f2bf(acc2[m][n][r]);
  __syncthreads();
#pragma unroll
  for (int it = 0; it < 2; ++it) {
    int t = it * 256 + tid;
    int r = t >> 3, c = (t & 7) * 8;
    *(int4*)(O + (size_t)(g * 64 + r) * 512 + h * 64 + c) = *(const int4*)(Os + r * 72 + c);
  }
}

// ---------------------------------------------------------------------------
// Attention over context axis (S=8, dh=64). QKV fused: [NT][1536] = Q|K|V.
// ---------------------------------------------------------------------------
__global__ __launch_bounds__(64) void attn_ctx(
    const ushort_t* __restrict__ QKV, ushort_t* __restrict__ O) {
  __shared__ float qs[8][72], ks[8][72], vs[8][72], ps[8][9];
  const int h = blockIdx.x & 7;
  const int l = (blockIdx.x >> 3) & 63;
  const int pb = blockIdx.x >> 9;
  const size_t row0 = (size_t)pb * 512 + l;
  const int tid = threadIdx.x;
  {
    int c = tid >> 3, dc = (tid & 7) * 8;
    size_t r = row0 + (size_t)c * 64;
    int4 qv = *(const int4*)(QKV + r * 1536 + h * 64 + dc);
    int4 kv = *(const int4*)(QKV + r * 1536 + 512 + h * 64 + dc);
    int4 vv = *(const int4*)(QKV + r * 1536 + 1024 + h * 64 + dc);
    unp2(qv.x, qs[c][dc + 0], qs[c][dc + 1]); unp2(qv.y, qs[c][dc + 2], qs[c][dc + 3]);
    unp2(qv.z, qs[c][dc + 4], qs[c][dc + 5]); unp2(qv.w, qs[c][dc + 6], qs[c][dc + 7]);
    unp2(kv.x, ks[c][dc + 0], ks[c][dc + 1]); unp2(kv.y, ks[c][dc + 2], ks[c][dc + 3]);
    unp2(kv.z, ks[c][dc + 4], ks[c][dc + 5]); unp2(kv.w, ks[c][dc + 6], ks[c][dc + 7]);
    unp2(vv.x, vs[c][dc + 0], vs[c][dc + 1]); unp2(vv.y, vs[c][dc + 2], vs[c][dc + 3]);
    unp2(vv.z, vs[c][dc + 4], vs[c][dc + 5]); unp2(vv.w, vs[c][dc + 6], vs[c][dc + 7]);
  }
  __syncthreads();
  {
    int i = tid >> 3, t = tid & 7;
    float s = 0.f;
#pragma unroll
    for (int d = 0; d < 64; ++d) s += qs[i][d] * ks[t][d];
    ps[i][t] = s * 0.125f;
  }
  __syncthreads();
  if (tid < 8) {
    float mx = -1e30f;
#pragma unroll
    for (int t = 0; t < 8; ++t) mx = fmaxf(mx, ps[tid][t]);
    float sum = 0.f;
#pragma unroll
    for (int t = 0; t < 8; ++t) { float e = __expf(ps[tid][t] - mx); ps[tid][t] = e; sum += e; }
    float inv = 1.f / sum;
#pragma unroll
    for (int t = 0; t < 8; ++t) ps[tid][t] *= inv;
  }
  __syncthreads();
#pragma unroll
  for (int c = 0; c < 8; ++c) {
    float s = 0.f;
#pragma unroll
    for (int t = 0; t < 8; ++t) s += ps[c][t] * vs[t][tid];
    O[(row0 + (size_t)c * 64) * D_ + h * 64 + tid] = f2bf(s);
  }
}

// ---------------------------------------------------------------------------
// Xout(bf16) = LN(Xin + T) * g + b. Residual stream bf16 (first call: f32 ex).
// ---------------------------------------------------------------------------
template <bool INF32>
__global__ __launch_bounds__(256) void add_ln(
    const void* Xin, const ushort_t* T, ushort_t* Xout,
    const float* __restrict__ g, const float* __restrict__ b) {
  const size_t off = (size_t)blockIdx.x * D_;
  const int tid = threadIdx.x;
  float x0, x1;
  if (INF32) {
    float2 xv = ((const float2*)((const float*)Xin + off))[tid];
    x0 = xv.x; x1 = xv.y;
  } else {
    ushort2 xv = ((const ushort2*)((const ushort_t*)Xin + off))[tid];
    x0 = bf2f(xv.x); x1 = bf2f(xv.y);
  }
  ushort2 tv = ((const ushort2*)(T + off))[tid];
  x0 += bf2f(tv.x);
  x1 += bf2f(tv.y);
  float s = x0 + x1, q = x0 * x0 + x1 * x1;
#pragma unroll
  for (int o = 32; o > 0; o >>= 1) { s += __shfl_down(s, o); q += __shfl_down(q, o); }
  __shared__ float ssum[4], sqsum[4];
  if ((tid & 63) == 0) { ssum[tid >> 6] = s; sqsum[tid >> 6] = q; }
  __syncthreads();
  float S = ssum[0] + ssum[1] + ssum[2] + ssum[3];
  float Qs = sqsum[0] + sqsum[1] + sqsum[2] + sqsum[3];
  float m = S * (1.f / D_);
  float var = Qs * (1.f / D_) - m * m;
  float inv = rsqrtf(var + 1e-5f);
  float y0 = (x0 - m) * inv * g[tid * 2] + b[tid * 2];
  float y1 = (x1 - m) * inv * g[tid * 2 + 1] + b[tid * 2 + 1];
  ushort2 ov; ov.x = f2bf(y0); ov.y = f2bf(y1);
  ((ushort2*)(Xout + off))[tid] = ov;
}

__global__ __launch_bounds__(512) void combine_last(
    const ushort_t* __restrict__ X, const float* __restrict__ gates,
    float* __restrict__ comb) {
  const int b = blockIdx.x >> 3, c = blockIdx.x & 7;
  const int d = threadIdx.x;
  float s = 0.f;
#pragma unroll
  for (int p = 0; p < PS; ++p) {
    size_t row = ((size_t)(p * BB + b) * CC + c) * LL + (LL - 1);
    s += gates[b * PS + p] * bf2f(X[row * D_ + d]);
  }
  comb[(size_t)blockIdx.x * D_ + d] = s;
}

__global__ __launch_bounds__(128) void head_kernel(
    const float* __restrict__ comb, const float* __restrict__ hW,
    const float* __restrict__ hb, float* __restrict__ out) {
  __shared__ float xr[D_];
  const int bc = blockIdx.x;
  for (int i = threadIdx.x; i < D_; i += 128) xr[i] = comb[(size_t)bc * D_ + i];
  __syncthreads();
  const int n = threadIdx.x;
  if (n < PREDN) {
    float s = hb[n];
    for (int d = 0; d < D_; ++d) s += xr[d] * hW[d * PREDN + n];
    const int b = bc >> 3, c = bc & 7;
    out[((size_t)b * PREDN + n) * CC + c] = s;
  }
}

// ---------------------------------------------------------------------------
extern "C" void kernel_launch(void* const* d_in, const int* in_sizes, int n_in,
                              void* d_out, int out_size, void* d_ws, size_t ws_size,
                              hipStream_t stream) {
  const float* ex    = (const float*)d_in[0];
  const float* gates = (const float*)d_in[1];
  const float* cWq = (const float*)d_in[2];  const float* cbq = (const float*)d_in[3];
  const float* cWk = (const float*)d_in[4];  const float* cbk = (const float*)d_in[5];
  const float* cWv = (const float*)d_in[6];  const float* cbv = (const float*)d_in[7];
  const float* cWo = (const float*)d_in[8];  const float* cbo = (const float*)d_in[9];
  const float* iWq = (const float*)d_in[10]; const float* ibq = (const float*)d_in[11];
  const float* iWk = (const float*)d_in[12]; const float* ibk = (const float*)d_in[13];
  const float* iWv = (const float*)d_in[14]; const float* ibv = (const float*)d_in[15];
  const float* iWo = (const float*)d_in[16]; const float* ibo = (const float*)d_in[17];
  const float* mW1 = (const float*)d_in[18]; const float* mb1 = (const float*)d_in[19];
  const float* mW2 = (const float*)d_in[20]; const float* mb2 = (const float*)d_in[21];
  const float* g1  = (const float*)d_in[22]; const float* b1  = (const float*)d_in[23];
  const float* g3  = (const float*)d_in[24]; const float* b3  = (const float*)d_in[25];
  const float* g4  = (const float*)d_in[26]; const float* b4  = (const float*)d_in[27];
  const float* hW  = (const float*)d_in[28]; const float* hb  = (const float*)d_in[29];
  float* out = (float*)d_out;

  // ---- workspace layout ----
  ushort_t* wqk  = (ushort_t*)d_ws;            // [1024][512] cWq^T | cWk^T
  ushort_t* wv   = wqk  + 524288;              // [512][512]
  ushort_t* wo   = wv   + 262144;
  ushort_t* wiqkv= wo   + 262144;              // [1536][512] iWq^T|iWk^T|iWv^T
  ushort_t* wio  = wiqkv+ 786432;
  ushort_t* w1   = wio  + 262144;              // [2048][512]
  ushort_t* w2   = w1   + 1048576;             // [512][2048]
  float*  bqk  = (float*)(w2 + 1048576);       // [1024] cbq|cbk
  float*  biqkv= bqk + 1024;                   // [1536] ibq|ibk|ibv
  ushort_t* Xb = (ushort_t*)(biqkv + 1536);    // bf16 residual stream, NT*512
  ushort_t* QKb = Xb + (size_t)NT * D_;        // [NT][1024] (blk1) / QKV [NT][1536] (blk2) / MLP H
  ushort_t* Vtb = QKb + (size_t)NT * 1024;     // [512][NT] (blk1) — part of QKV/H region
  ushort_t* Ob  = Vtb + (size_t)NT * D_;       // [NT][512] attn out / H part 3
  ushort_t* Tb  = Ob + (size_t)NT * D_;        // [NT][512] MLP out (disjoint from H)
  float*   comb = (float*)(Tb + (size_t)NT * D_);

  // ---- weight/bias prep ----
  transpose_bf16<<<dim3(16, 16), 256, 0, stream>>>(cWq, wqk, 512, 512);
  transpose_bf16<<<dim3(16, 16), 256, 0, stream>>>(cWk, wqk + 262144, 512, 512);
  transpose_bf16<<<dim3(16, 16), 256, 0, stream>>>(cWv, wv, 512, 512);
  transpose_bf16<<<dim3(16, 16), 256, 0, stream>>>(cWo, wo, 512, 512);
  transpose_bf16<<<dim3(16, 16), 256, 0, stream>>>(iWq, wiqkv, 512, 512);
  transpose_bf16<<<dim3(16, 16), 256, 0, stream>>>(iWk, wiqkv + 262144, 512, 512);
  transpose_bf16<<<dim3(16, 16), 256, 0, stream>>>(iWv, wiqkv + 524288, 512, 512);
  transpose_bf16<<<dim3(16, 16), 256, 0, stream>>>(iWo, wio, 512, 512);
  transpose_bf16<<<dim3(16, 64), 256, 0, stream>>>(mW1, w1, 512, 2048);
  transpose_bf16<<<dim3(64, 16), 256, 0, stream>>>(mW2, w2, 2048, 512);
  hipMemcpyAsync(bqk, cbq, 512 * 4, hipMemcpyDeviceToDevice, stream);
  hipMemcpyAsync(bqk + 512, cbk, 512 * 4, hipMemcpyDeviceToDevice, stream);
  hipMemcpyAsync(biqkv, ibq, 512 * 4, hipMemcpyDeviceToDevice, stream);
  hipMemcpyAsync(biqkv + 512, ibk, 512 * 4, hipMemcpyDeviceToDevice, stream);
  hipMemcpyAsync(biqkv + 1024, ibv, 512 * 4, hipMemcpyDeviceToDevice, stream);
  conv_bf16<<<dim3(NT * D_ / 8 / 256), 256, 0, stream>>>(ex, Xb, NT * D_ / 8);

  dim3 blk(512);
  const int RT = NT / 256;  // 192 row tiles (BM=256)

  // ---- block 1: attention over L ----
  gemm_mfma<false, false><<<dim3(RT * 8), blk, 0, stream>>>(Xb, wqk, bqk, QKb, NT, 1024, 512);
  gemm_mfma<false, true ><<<dim3(2 * (NT / 128)), blk, 0, stream>>>(wv, Xb, cbv, Vtb, 512, NT, 512);
  attn_seq_mfma<<<dim3(768 * 8), dim3(256), 0, stream>>>(QKb, Vtb, Ob);
  gemm_mfma<false, false><<<dim3(RT * 4), blk, 0, stream>>>(Ob, wo, cbo, Tb, NT, 512, 512);
  add_ln<true><<<dim3(NT), dim3(256), 0, stream>>>(ex, Tb, Xb, g1, b1);

  // ---- block 2: attention over C (fused QKV, N=1536) ----
  gemm_mfma<false, false><<<dim3(RT * 12), blk, 0, stream>>>(Xb, wiqkv, biqkv, QKb, NT, 1536, 512);
  attn_ctx<<<dim3(NT), dim3(64), 0, stream>>>(QKb, Ob);
  gemm_mfma<false, false><<<dim3(RT * 4), blk, 0, stream>>>(Ob, wio, ibo, Tb, NT, 512, 512);
  add_ln<false><<<dim3(NT), dim3(256), 0, stream>>>(Xb, Tb, Xb, g3, b3);

  // ---- MLP: hidden H (bf16 NT*2048) overlays QKb..Ob; out -> Tb ----
  gemm_mfma<true,  false><<<dim3(RT * 16), blk, 0, stream>>>(Xb, w1, mb1, QKb, NT, 2048, 512);
  gemm_mfma<false, false><<<dim3(RT * 4),  blk, 0, stream>>>(QKb, w2, mb2, Tb, NT, 512, 2048);
  add_ln<false><<<dim3(NT), dim3(256), 0, stream>>>(Xb, Tb, Xb, g4, b4);

  // ---- gated combine + head ----
  combine_last<<<dim3(BB * CC), dim3(512), 0, stream>>>(Xb, gates, comb);
  head_kernel<<<dim3(BB * CC), dim3(128), 0, stream>>>(comb, hW, hb, out);
}